// Round 9
// baseline (241.215 us; speedup 1.0000x reference)
//
#include <hip/hip_runtime.h>

typedef __attribute__((ext_vector_type(8))) short bf16x8;   // 8 bf16 = 4 VGPRs
typedef __attribute__((ext_vector_type(4))) float f32x4;

#define MFMA16(a, b, c) __builtin_amdgcn_mfma_f32_16x16x32_bf16((a), (b), (c), 0, 0, 0)

__device__ __forceinline__ float bf2f(unsigned short h) {
    union { unsigned int u; float f; } v; v.u = ((unsigned int)h) << 16; return v.f;
}
__device__ __forceinline__ unsigned short f2bf(float f) {
    union { float f; unsigned int u; } v; v.f = f;
    unsigned int u = v.u;
    return (unsigned short)((u + 0x7fffu + ((u >> 16) & 1u)) >> 16);  // RNE
}

// Async global->LDS, 16B per lane (wave-uniform base + lane*16 layout).
__device__ __forceinline__ void gload16(const void* g, void* l) {
    __builtin_amdgcn_global_load_lds(
        (const __attribute__((address_space(1))) unsigned int*)(unsigned long long)g,
        (__attribute__((address_space(3))) unsigned int*)(unsigned int)(unsigned long long)l,
        16, 0, 0);
}

// ---------------------------------------------------------------------------
// Dtype probe: flag=1 -> fp32 buffers, 0 -> bf16. (R2/R3/R6/R7 confirmed fp32.)
// ---------------------------------------------------------------------------
__global__ void k_probe(const unsigned int* __restrict__ x, int* __restrict__ flag) {
    int lane = threadIdx.x;                     // 64 threads
    unsigned int bad = 0;
#pragma unroll
    for (int i = 0; i < 4; ++i) {
        unsigned int u = x[lane + 64 * i];
        unsigned int e = (u >> 7) & 0xFFu;
        if (e >= 0x90u) bad = 1;
    }
    unsigned long long m = __ballot(bad != 0);
    if (lane == 0) *flag = (m != 0ull) ? 1 : 0;
}

// ---------------------------------------------------------------------------
// Convert x, b_in, b_out into bf16 staging (contiguous).
// ---------------------------------------------------------------------------
__global__ __launch_bounds__(256) void k_convert(const void* __restrict__ x,
        const void* __restrict__ b_in, const void* __restrict__ b_out,
        unsigned short* __restrict__ dst, const int* __restrict__ flag)
{
    const int isf = *flag;
    const long long N0 = 4194304, N1 = N0 + 3072, N2 = N1 + 1024;
    long long stride = (long long)gridDim.x * 256;
    for (long long idx = (long long)blockIdx.x * 256 + threadIdx.x; idx < N2; idx += stride) {
        const void* src; long long off;
        if (idx < N0)      { src = x;     off = idx; }
        else if (idx < N1) { src = b_in;  off = idx - N0; }
        else               { src = b_out; off = idx - N1; }
        dst[idx] = isf ? f2bf(((const float*)src)[off])
                       : ((const unsigned short*)src)[off];
    }
}

// ---------------------------------------------------------------------------
// Transpose src[K][N] -> dst[N][K] bf16. 64x64 tiles, full coverage.
// ---------------------------------------------------------------------------
__global__ __launch_bounds__(256) void k_transpose(const void* __restrict__ src,
        unsigned short* __restrict__ dst, int K, int N, const int* __restrict__ flag)
{
    __shared__ unsigned short ls[64][72];
    const int isf = *flag;
    const int tid = threadIdx.x;
    const int n0 = blockIdx.x * 64, k0 = blockIdx.y * 64;
    const int r = tid >> 2, c = (tid & 3) * 16;
    union { uint4 v[2]; unsigned short s[16]; } p;
    if (isf) {
        const float* s = (const float*)src + (long long)(k0 + r) * N + n0 + c;
#pragma unroll
        for (int q4 = 0; q4 < 4; ++q4) {
            float4 f = *(const float4*)(s + q4 * 4);
            p.s[q4 * 4 + 0] = f2bf(f.x); p.s[q4 * 4 + 1] = f2bf(f.y);
            p.s[q4 * 4 + 2] = f2bf(f.z); p.s[q4 * 4 + 3] = f2bf(f.w);
        }
    } else {
        const unsigned short* s = (const unsigned short*)src + (long long)(k0 + r) * N + n0 + c;
        p.v[0] = *(const uint4*)s;
        p.v[1] = *(const uint4*)(s + 8);
    }
    *(uint4*)&ls[r][c]     = p.v[0];
    *(uint4*)&ls[r][c + 8] = p.v[1];
    __syncthreads();
    union { uint4 v[2]; unsigned short s[16]; } q;
#pragma unroll
    for (int j = 0; j < 16; ++j) q.s[j] = ls[c + j][r];
    unsigned short* d = dst + (long long)(n0 + r) * K + k0 + c;
    *(uint4*)d = q.v[0];
    *(uint4*)(d + 8) = q.v[1];
}

// ---------------------------------------------------------------------------
// 128x128 GEMM core (m97 structure): C = A[128xK] * BT[128xK]^T, bf16/fp32acc.
// global_load_lds width-16 staging, BK=32, 2 barriers/iter.
// ---------------------------------------------------------------------------
__device__ __forceinline__ void gemm_core(const unsigned short* A, int lda,
        const unsigned short* BT, int ldb, int K,
        unsigned short* lA, unsigned short* lB, f32x4 acc[4][4])
{
    const int tid = threadIdx.x;
    const int w = tid >> 6, wr = w >> 1, wc = w & 1;
    const int lane = tid & 63, quad = lane >> 4, li = lane & 15;
    const int sr = tid >> 2, sk = (tid & 3) * 8;
    const unsigned short* ag = A + (long long)sr * lda + sk;
    const unsigned short* bg = BT + (long long)sr * ldb + sk;
    for (int k0 = 0; k0 < K; k0 += 32) {
        gload16(ag,            lA + tid * 8);
        gload16(ag + 64 * lda, lA + 2048 + tid * 8);
        gload16(bg,            lB + tid * 8);
        gload16(bg + 64 * ldb, lB + 2048 + tid * 8);
        ag += 32; bg += 32;
        __syncthreads();                       // drains vmcnt (compiler-inserted)
        bf16x8 af[4], bfr[4];
#pragma unroll
        for (int i = 0; i < 4; ++i) {
            af[i]  = *(const bf16x8*)(lA + (wr * 64 + i * 16 + li) * 32 + quad * 8);
            bfr[i] = *(const bf16x8*)(lB + (wc * 64 + i * 16 + li) * 32 + quad * 8);
        }
#pragma unroll
        for (int at = 0; at < 4; ++at)
#pragma unroll
            for (int bt = 0; bt < 4; ++bt)
                acc[at][bt] = MFMA16(af[at], bfr[bt], acc[at][bt]);
        __syncthreads();                       // reads done before next staging
    }
}

// ---------------------------------------------------------------------------
// QKV projection: 128x128 tiles, grid (32, 24).
// ---------------------------------------------------------------------------
__global__ __launch_bounds__(256) void k_gemm_qkv(const unsigned short* __restrict__ x,
        const unsigned short* __restrict__ w_inT, const unsigned short* __restrict__ b_in,
        unsigned short* __restrict__ qws, unsigned short* __restrict__ kws,
        unsigned short* __restrict__ vtws)
{
    __shared__ unsigned short sm[17408];                 // lA|lB staging, then lC
    unsigned short (*lC)[136] = (unsigned short (*)[136])sm;
    const int gm0 = blockIdx.x * 128, gn0 = blockIdx.y * 128;
    f32x4 acc[4][4];
#pragma unroll
    for (int i = 0; i < 4; ++i)
#pragma unroll
        for (int j = 0; j < 4; ++j) acc[i][j] = (f32x4){0.f, 0.f, 0.f, 0.f};
    gemm_core(x + (long long)gm0 * 1024, 1024, w_inT + (long long)gn0 * 1024, 1024, 1024,
              sm, sm + 4096, acc);

    const int tid = threadIdx.x, w = tid >> 6, wr = w >> 1, wc = w & 1;
    const int lane = tid & 63, quad = lane >> 4, li = lane & 15;
    const float qscale = (gn0 < 1024) ? 0.03125f : 1.0f;
#pragma unroll
    for (int at = 0; at < 4; ++at)
#pragma unroll
        for (int bt = 0; bt < 4; ++bt)
#pragma unroll
            for (int r = 0; r < 4; ++r) {
                int row = wr * 64 + at * 16 + quad * 4 + r;
                int col = wc * 64 + bt * 16 + li;
                lC[row][col] = f2bf((acc[at][bt][r] + bf2f(b_in[gn0 + col])) * qscale);
            }
    __syncthreads();
    const int region = gn0 >> 10, h0 = (gn0 & 1023) >> 6, b = gm0 >> 10, s0 = gm0 & 1023;
    if (region < 2) {                                    // q or k
        unsigned short* base = (region == 0 ? qws : kws);
        int mm = tid >> 1, hh = tid & 1;
        unsigned short* dst = base + ((long long)(b * 16 + h0 + hh) * 1024 + s0 + mm) * 64;
#pragma unroll
        for (int j = 0; j < 8; ++j)
            *(uint4*)(dst + j * 8) = *(const uint4*)&lC[mm][hh * 64 + j * 8];
    } else {                                             // v transposed
        int d = tid >> 2, sub = tid & 3, hh = sub >> 1, cs = (sub & 1) * 64;
        unsigned short* dst = vtws + ((long long)(b * 16 + h0 + hh) * 64 + d) * 1024 + s0 + cs;
#pragma unroll
        for (int j8 = 0; j8 < 8; ++j8) {
            union { uint4 v; unsigned short s[8]; } p;
#pragma unroll
            for (int i = 0; i < 8; ++i) p.s[i] = lC[cs + j8 * 8 + i][hh * 64 + d];
            *(uint4*)(dst + j8 * 8) = p.v;
        }
    }
}

// ---------------------------------------------------------------------------
// DIRECT attention, R16: R15 + DOUBLE-BUFFERED K/V staging (T3 min-2-phase).
// Chunk c+1's global_load_lds issues BEFORE compute of chunk c, so the
// end-of-chunk barrier's vmcnt(0) drain waits only for latency not already
// covered by ~2K cycles of MFMA/exp/PV. One barrier per chunk (was 2).
// LDS 2x(8K+8K) staging + 32K P = 64KB -> 2 blocks/CU (unchanged).
// Block = 4 waves x 32 q-rows, one head; swizzled staging per R15 (verified:
// +0 bank conflicts). Fused unnormalized mpart store; linvg reciprocals.
// Grid (8,4,16) x 256 thr; XCD swizzle: 8 heads/XCD.
// ---------------------------------------------------------------------------
__global__ __launch_bounds__(256, 2)
void k_attn_d(const unsigned short* __restrict__ qw,
        const unsigned short* __restrict__ kw, const unsigned short* __restrict__ vtw,
        unsigned short* __restrict__ ows, unsigned short* __restrict__ mpart,
        float* __restrict__ linvg)
{
    __shared__ unsigned short lK[2][8192];        // dbuf: 128 k-rows x 64 d, swizzled
    __shared__ unsigned short lV[2][8192];        // dbuf: 64 d-rows x 128 s, swizzled
    __shared__ unsigned short P[4][8][32][16];    // per-wave P, 8KB each

    const int lin = blockIdx.x + (blockIdx.y << 3) + (blockIdx.z << 5);
    const int work = (lin >> 3) + ((lin & 7) << 6);       // bijective: 512 = 8*64
    const int qt = work & 7, u = work >> 3;               // u = b*16+h, 0..63
    const int tid = threadIdx.x, w = tid >> 6, lane = tid & 63;
    const int quad = lane >> 4, li = lane & 15;
    const int q0w = qt * 128 + w * 32;
    const int h = u & 15, brow = (u >> 4) * 1024;
    unsigned short (*Pw)[32][16] = P[w];

    const unsigned short* qb = qw + ((long long)u * 1024 + q0w + li) * 64 + quad * 8;
    bf16x8 qA0 = *(const bf16x8*)qb;              // q-half A: rows q0w+li
    bf16x8 qA1 = *(const bf16x8*)(qb + 32);
    bf16x8 qB0 = *(const bf16x8*)(qb + 1024);     // q-half B: rows q0w+16+li
    bf16x8 qB1 = *(const bf16x8*)(qb + 1024 + 32);

    const unsigned short* kbh = kw + (long long)u * 65536;
    const unsigned short* vbh = vtw + (long long)u * 65536;
    unsigned short* mp = mpart + ((long long)h << 22);
    const long long rowoffA = (long long)(brow + q0w + li) * 1024;
    const long long rowoffB = rowoffA + 16 * 1024;

    float rsA[4] = {0.f, 0.f, 0.f, 0.f}, rsB[4] = {0.f, 0.f, 0.f, 0.f};
    f32x4 oaccA[4] = {{0,0,0,0},{0,0,0,0},{0,0,0,0},{0,0,0,0}};
    f32x4 oaccB[4] = {{0,0,0,0},{0,0,0,0},{0,0,0,0},{0,0,0,0}};

    // ---- staging: contiguous gload16, source pre-swizzled (m173 pattern).
    //      K slot t (16B units): r=t>>3, holds global d-chunk (t&7)^(r&7).
    //      V slot t: d=t>>4, holds global s-chunk (t&15)^(d&15).
#define STAGE_KV(c, buf)                                                      \
    {                                                                         \
        _Pragma("unroll")                                                     \
        for (int p = 0; p < 4; ++p) {                                         \
            int t = p * 256 + tid;                                            \
            int kr = t >> 3, kcg = (t & 7) ^ (kr & 7);                        \
            gload16(kbh + (c) * 8192 + kr * 64 + kcg * 8, lK[buf] + t * 8);   \
            int vd = t >> 4, vcg = (t & 15) ^ (vd & 15);                      \
            gload16(vbh + vd * 1024 + (c) * 128 + vcg * 8, lV[buf] + t * 8);  \
        }                                                                     \
    }

    STAGE_KV(0, 0);
    __syncthreads();                              // chunk 0 staged

    for (int c = 0; c < 8; ++c) {
        const int cur = c & 1;
        if (c < 7) STAGE_KV(c + 1, cur ^ 1);      // async prefetch overlaps compute
        const unsigned short* lKc = lK[cur];
        const unsigned short* lVc = lV[cur];
        // ---- score: 8 kt tiles -> 2 q-halves -> exp -> P (own-wave LDS) ----
#pragma unroll
        for (int kt = 0; kt < 8; ++kt) {
            int b16 = (kt * 16 + li) * 8 + (quad ^ (li & 7));   // swizzled slot
            bf16x8 kf0 = *(const bf16x8*)(lKc + b16 * 8);
            bf16x8 kf1 = *(const bf16x8*)(lKc + (b16 ^ 4) * 8); // d-chunk+4
            f32x4 a = {0.f, 0.f, 0.f, 0.f};
            a = MFMA16(qA0, kf0, a);
            a = MFMA16(qA1, kf1, a);
            f32x4 a2 = {0.f, 0.f, 0.f, 0.f};
            a2 = MFMA16(qB0, kf0, a2);
            a2 = MFMA16(qB1, kf1, a2);
#pragma unroll
            for (int r = 0; r < 4; ++r) {
                float p = __expf(a[r]);
                rsA[r] += p;
                Pw[kt][quad * 4 + r][li] = f2bf(p);
                float p2 = __expf(a2[r]);
                rsB[r] += p2;
                Pw[kt][16 + quad * 4 + r][li] = f2bf(p2);
            }
        }
        // ---- PV on unnormalized P + fused mpart store; V via swizzled LDS ----
#pragma unroll
        for (int t = 0; t < 4; ++t) {
            union { bf16x8 v; uint4 u4; } paA, paB;
            paA.v = *(const bf16x8*)&Pw[2 * t + (quad >> 1)][li][(quad & 1) * 8];
            paB.v = *(const bf16x8*)&Pw[2 * t + (quad >> 1)][16 + li][(quad & 1) * 8];
            *(uint4*)(mp + rowoffA + c * 128 + t * 32 + quad * 8) = paA.u4;
            *(uint4*)(mp + rowoffB + c * 128 + t * 32 + quad * 8) = paB.u4;
#pragma unroll
            for (int nt = 0; nt < 4; ++nt) {
                int idx = (nt * 16 + li) * 16 + ((t * 4 + quad) ^ li);
                bf16x8 vf = *(const bf16x8*)(lVc + idx * 8);
                oaccA[nt] = MFMA16(paA.v, vf, oaccA[nt]);
                oaccB[nt] = MFMA16(paB.v, vf, oaccB[nt]);
            }
        }
        if (c < 7) __syncthreads();               // next chunk staged + reads done
    }
#undef STAGE_KV
    // ---- complete row sums: shuffle-reduce over li (k-cols; within quad) ----
#pragma unroll
    for (int r = 0; r < 4; ++r) {
        float sA = rsA[r], sB = rsB[r];
#pragma unroll
        for (int d = 1; d < 16; d <<= 1) { sA += __shfl_xor(sA, d, 64); sB += __shfl_xor(sB, d, 64); }
        rsA[r] = 1.f / sA;
        rsB[r] = 1.f / sB;
    }
    if (li == 0) {
        float* lg = linvg + ((long long)h << 12) + brow + q0w + quad * 4;
#pragma unroll
        for (int r = 0; r < 4; ++r) { lg[r] = rsA[r]; lg[16 + r] = rsB[r]; }
    }
    // ---- direct ows store: q = (qh*16)+quad*4+r, d = nt*16+li ----
    unsigned short* ob = ows + (long long)(brow + q0w) * 1024 + h * 64;
#pragma unroll
    for (int r = 0; r < 4; ++r) {
#pragma unroll
        for (int nt = 0; nt < 4; ++nt) {
            ob[(quad * 4 + r) * 1024 + nt * 16 + li]      = f2bf(oaccA[nt][r] * rsA[r]);
            ob[(16 + quad * 4 + r) * 1024 + nt * 16 + li] = f2bf(oaccB[nt][r] * rsB[r]);
        }
    }
}

// ---------------------------------------------------------------------------
// DIRECT combine: 16 UNNORMALIZED planes x linv[g][row] (reciprocal already
// computed by attn), then x 1/16.
// ---------------------------------------------------------------------------
__global__ __launch_bounds__(256) void k_mean_combine_linv(const unsigned short* __restrict__ mp,
        const float* __restrict__ linvg, void* __restrict__ dout, const int* __restrict__ flag)
{
    const int isf = *flag;
    long long idx = ((long long)blockIdx.x * 256 + threadIdx.x) * 8;
    const int row = (int)(idx >> 10);             // b*1024 + q, 0..4095
    float o[8] = {0, 0, 0, 0, 0, 0, 0, 0};
    for (int g = 0; g < 16; ++g) {
        float linv = linvg[((long long)g << 12) + row];
        union { uint4 v; unsigned short s[8]; } p;
        p.v = *(const uint4*)(mp + ((long long)g << 22) + idx);
#pragma unroll
        for (int j = 0; j < 8; ++j) o[j] += bf2f(p.s[j]) * linv;
    }
#pragma unroll
    for (int j = 0; j < 8; ++j) o[j] *= 0.0625f;
    if (isf) {
        float* dst = (float*)dout + 4194304 + idx;
        float4 a = {o[0], o[1], o[2], o[3]}, bq = {o[4], o[5], o[6], o[7]};
        *(float4*)dst = a;
        *(float4*)(dst + 4) = bq;
    } else {
        union { uint4 v; unsigned short s[8]; } pk;
#pragma unroll
        for (int j = 0; j < 8; ++j) pk.s[j] = f2bf(o[j]);
        *(uint4*)((unsigned short*)dout + 4194304 + idx) = pk.v;
    }
}

// ---------------------------------------------------------------------------
// Fallback fused attention (non-DIRECT ws sizes), unchanged from R7.
// ---------------------------------------------------------------------------
template<bool DIRECT>
__global__ __launch_bounds__(256, DIRECT ? 4 : 2)
void k_attn(const unsigned short* __restrict__ qw,
        const unsigned short* __restrict__ kw, const unsigned short* __restrict__ vtw,
        unsigned short* __restrict__ ows, unsigned short* __restrict__ mpart,
        float* __restrict__ lsumg, int hpg)
{
    __shared__ unsigned short P[4][16][16][16];   // 32 KB, per-wave [kt][row][col16]
    __shared__ float red[4][16];
    float (*obuf)[16][65] = (float (*)[16][65])&P[0][0][0][0];   // alias, used late
    const int b = blockIdx.y, q0 = blockIdx.x * 16, g = blockIdx.z;
    const int tid = threadIdx.x, w = tid >> 6, lane = tid & 63, quad = lane >> 4, li = lane & 15;

    float mean_acc[DIRECT ? 1 : 64];
    if constexpr (!DIRECT) {
#pragma unroll
        for (int i = 0; i < 64; ++i) mean_acc[i] = 0.f;
    }

    for (int hh = 0; hh < hpg; ++hh) {
        const int h = g * hpg + hh;
        const unsigned short* qb = qw + ((long long)(b * 16 + h) * 1024 + q0 + li) * 64 + quad * 8;
        bf16x8 qf0 = *(const bf16x8*)qb;
        bf16x8 qf1 = *(const bf16x8*)(qb + 32);

        // ---- score pass: MFMA -> exp -> P(LDS) + row-sum ----
        float rsum[4] = {0.f, 0.f, 0.f, 0.f};
        const unsigned short* kbh = kw + (long long)(b * 16 + h) * 65536;
#pragma unroll
        for (int kt = 0; kt < 16; ++kt) {
            const unsigned short* kb = kbh + (w * 256 + kt * 16 + li) * 64 + quad * 8;
            bf16x8 kf0 = *(const bf16x8*)kb;
            bf16x8 kf1 = *(const bf16x8*)(kb + 32);
            f32x4 a = {0.f, 0.f, 0.f, 0.f};
            a = MFMA16(qf0, kf0, a);
            a = MFMA16(qf1, kf1, a);
#pragma unroll
            for (int r = 0; r < 4; ++r) {
                float p = __expf(a[r]);
                rsum[r] += p;
                P[w][kt][quad * 4 + r][li] = f2bf(p);
            }
        }
#pragma unroll
        for (int r = 0; r < 4; ++r) {
            float s = rsum[r];
#pragma unroll
            for (int d = 1; d < 16; d <<= 1) s += __shfl_xor(s, d, 64);
            rsum[r] = s;
        }
        if (li == 0) {
#pragma unroll
            for (int r = 0; r < 4; ++r) red[w][quad * 4 + r] = rsum[r];
        }
        // ---- PV on UNNORMALIZED P (own-wave LDS, pre-barrier) ----
        f32x4 oacc[4] = {{0,0,0,0},{0,0,0,0},{0,0,0,0},{0,0,0,0}};
        const unsigned short* vbh = vtw + (long long)(b * 16 + h) * 65536;
        unsigned short* mp = mpart + ((long long)h << 22);
        const long long rowoff2 = (long long)(b * 1024 + q0 + li) * 1024 + w * 256;
#pragma unroll
        for (int t = 0; t < 8; ++t) {
            union { bf16x8 v; uint4 u; } pa;
            pa.v = *(const bf16x8*)&P[w][2 * t + (quad >> 1)][li][(quad & 1) * 8];
            if constexpr (DIRECT)
                *(uint4*)(mp + rowoff2 + t * 32 + quad * 8) = pa.u;
            const int sv0 = w * 256 + t * 32;
#pragma unroll
            for (int nt = 0; nt < 4; ++nt) {
                const unsigned short* vb = vbh + (nt * 16 + li) * 1024 + sv0 + quad * 8;
                bf16x8 vf = *(const bf16x8*)vb;
                oacc[nt] = MFMA16(pa.v, vf, oacc[nt]);
            }
        }
        __syncthreads();                          // red ready AND all P reads done
        float linv[4];
#pragma unroll
        for (int r = 0; r < 4; ++r)
            linv[r] = 1.f / (red[0][quad * 4 + r] + red[1][quad * 4 + r] +
                             red[2][quad * 4 + r] + red[3][quad * 4 + r]);
        if constexpr (DIRECT) {
            if (tid < 16) {
                float s = red[0][tid] + red[1][tid] + red[2][tid] + red[3][tid];
                lsumg[((long long)h << 12) + b * 1024 + q0 + tid] = s;
            }
        } else {
            float lrow = 1.f / (red[0][li] + red[1][li] + red[2][li] + red[3][li]);
#pragma unroll
            for (int t = 0; t < 8; ++t) {
                union { bf16x8 v; unsigned short s[8]; } pa;
                pa.v = *(const bf16x8*)&P[w][2 * t + (quad >> 1)][li][(quad & 1) * 8];
#pragma unroll
                for (int j = 0; j < 8; ++j) mean_acc[t * 8 + j] += bf2f(pa.s[j]) * lrow;
            }
            __syncthreads();                      // all P reads done before obuf alias
        }
#pragma unroll
        for (int nt = 0; nt < 4; ++nt)
#pragma unroll
            for (int r = 0; r < 4; ++r)
                obuf[w][quad * 4 + r][nt * 16 + li] = oacc[nt][r] * linv[r];
        __syncthreads();
        {
            int row = tid >> 4, c4 = (tid & 15) * 4;
            union { uint2 v2; unsigned short s[4]; } pk;
#pragma unroll
            for (int j = 0; j < 4; ++j) {
                float s = obuf[0][row][c4 + j] + obuf[1][row][c4 + j] +
                          obuf[2][row][c4 + j] + obuf[3][row][c4 + j];
                pk.s[j] = f2bf(s);
            }
            *(uint2*)(ows + ((long long)(b * 1024) + q0 + row) * 1024 + h * 64 + c4) = pk.v2;
        }
        if (hh + 1 < hpg) __syncthreads();        // obuf reads done before next head
    }
    if constexpr (!DIRECT) {
        unsigned short* mp = mpart + ((long long)g << 22);
        long long rowoff2 = (long long)(b * 1024 + q0 + li) * 1024 + w * 256;
#pragma unroll
        for (int t = 0; t < 8; ++t) {
            union { uint4 v; unsigned short s[8]; } u;
#pragma unroll
            for (int j = 0; j < 8; ++j) u.s[j] = f2bf(mean_acc[t * 8 + j]);
            *(uint4*)(mp + rowoff2 + t * 32 + quad * 8) = u.v;
        }
    }
}

// ---------------------------------------------------------------------------
// Fallback combine (normalized partial planes, ng groups), unchanged.
// ---------------------------------------------------------------------------
__global__ __launch_bounds__(256) void k_mean_combine(const unsigned short* __restrict__ mp,
        void* __restrict__ dout, const int* __restrict__ flag, int ng)
{
    const int isf = *flag;
    long long idx = ((long long)blockIdx.x * 256 + threadIdx.x) * 8;
    float o[8] = {0, 0, 0, 0, 0, 0, 0, 0};
    for (int g = 0; g < ng; ++g) {
        union { uint4 v; unsigned short s[8]; } p;
        p.v = *(const uint4*)(mp + ((long long)g << 22) + idx);
#pragma unroll
        for (int j = 0; j < 8; ++j) o[j] += bf2f(p.s[j]);
    }
#pragma unroll
    for (int j = 0; j < 8; ++j) o[j] *= 0.0625f;
    if (isf) {
        float* dst = (float*)dout + 4194304 + idx;
        float4 a = {o[0], o[1], o[2], o[3]}, bq = {o[4], o[5], o[6], o[7]};
        *(float4*)dst = a;
        *(float4*)(dst + 4) = bq;
    } else {
        union { uint4 v; unsigned short s[8]; } pk;
#pragma unroll
        for (int j = 0; j < 8; ++j) pk.s[j] = f2bf(o[j]);
        *(uint4*)((unsigned short*)dout + 4194304 + idx) = pk.v;
    }
}

// ---------------------------------------------------------------------------
// Output projection: 128x128 tiles, grid (32, 8).
// ---------------------------------------------------------------------------
__global__ __launch_bounds__(256) void k_gemm_out(const unsigned short* __restrict__ aws,
        const unsigned short* __restrict__ w_outT, const unsigned short* __restrict__ b_out,
        void* __restrict__ dout, const int* __restrict__ flag)
{
    __shared__ unsigned short sm[17408];
    unsigned short (*lC)[136] = (unsigned short (*)[136])sm;
    const int gm0 = blockIdx.x * 128, gn0 = blockIdx.y * 128;
    const int isf = *flag;
    f32x4 acc[4][4];
#pragma unroll
    for (int i = 0; i < 4; ++i)
#pragma unroll
        for (int j = 0; j < 4; ++j) acc[i][j] = (f32x4){0.f, 0.f, 0.f, 0.f};
    gemm_core(aws + (long long)gm0 * 1024, 1024, w_outT + (long long)gn0 * 1024, 1024, 1024,
              sm, sm + 4096, acc);

    const int tid = threadIdx.x, w = tid >> 6, wr = w >> 1, wc = w & 1;
    const int lane = tid & 63, quad = lane >> 4, li = lane & 15;
#pragma unroll
    for (int at = 0; at < 4; ++at)
#pragma unroll
        for (int bt = 0; bt < 4; ++bt)
#pragma unroll
            for (int r = 0; r < 4; ++r) {
                int row = wr * 64 + at * 16 + quad * 4 + r;
                int col = wc * 64 + bt * 16 + li;
                lC[row][col] = f2bf(acc[at][bt][r] + bf2f(b_out[gn0 + col]));
            }
    __syncthreads();
    int mm = tid >> 1, ch = (tid & 1) * 64;
    if (isf) {
        float* dst = (float*)dout + (long long)(gm0 + mm) * 1024 + gn0 + ch;
#pragma unroll
        for (int j4 = 0; j4 < 16; ++j4) {
            float4 f;
            f.x = bf2f(lC[mm][ch + j4 * 4 + 0]);
            f.y = bf2f(lC[mm][ch + j4 * 4 + 1]);
            f.z = bf2f(lC[mm][ch + j4 * 4 + 2]);
            f.w = bf2f(lC[mm][ch + j4 * 4 + 3]);
            *(float4*)(dst + j4 * 4) = f;
        }
    } else {
        unsigned short* dst = (unsigned short*)dout + (long long)(gm0 + mm) * 1024 + gn0 + ch;
#pragma unroll
        for (int j = 0; j < 8; ++j)
            *(uint4*)(dst + j * 8) = *(const uint4*)&lC[mm][ch + j * 8];
    }
}

// ---------------------------------------------------------------------------
// ws layout (shorts): [flag 256][xb/ows 4.19M][b_in 3072][b_out 1024]
// [w_outT 1.05M][qws 4.19M][kws 4.19M][vtws 4.19M][w_inT 3.15M | mpart 16 x
// 4.19M (alias; w_inT dead after qkv)]. ng=16 needs 169,878,016 B — R7
// measured this branch taken and passing. linv (256 KB fp32) lives at the
// START of d_out's `out` region: written by k_attn_d, read by
// k_mean_combine_linv, then overwritten by k_gemm_out (same-stream order).
// ---------------------------------------------------------------------------
extern "C" void kernel_launch(void* const* d_in, const int* in_sizes, int n_in,
                              void* d_out, int out_size, void* d_ws, size_t ws_size,
                              hipStream_t stream)
{
    int* flag = (int*)d_ws;
    unsigned short* xb     = (unsigned short*)d_ws + 256;      // 4,194,304
    unsigned short* b_inb  = xb + 4194304;                     // 3,072
    unsigned short* b_outb = b_inb + 3072;                     // 1,024
    unsigned short* w_outT = b_outb + 1024;                    // 1,048,576
    unsigned short* qws    = w_outT + 1048576;                 // 4,194,304
    unsigned short* kws    = qws + 4194304;                    // 4,194,304
    unsigned short* vtws   = kws + 4194304;                    // 4,194,304
    unsigned short* w_inT  = vtws + 4194304;                   // 3,145,728 (dead after qkv)
    unsigned short* mpart  = w_inT;                            // 16 x 4,194,304 (alias)
    unsigned short* ows    = xb;                               // reuse x staging (dead)
    float* lsumf           = (float*)d_out;                    // 64K fp32 scratch (dead until gemm_out)

    k_probe<<<1, 64, 0, stream>>>((const unsigned int*)d_in[0], flag);
    k_convert<<<4096, 256, 0, stream>>>(d_in[0], d_in[2], d_in[4], xb, flag);
    k_transpose<<<dim3(48, 16), 256, 0, stream>>>(d_in[1], w_inT, 1024, 3072, flag);
    k_transpose<<<dim3(16, 16), 256, 0, stream>>>(d_in[3], w_outT, 1024, 1024, flag);
    k_gemm_qkv<<<dim3(32, 24), 256, 0, stream>>>(xb, w_inT, b_inb, qws, kws, vtws);

    if (ws_size >= 169878016ull) {                             // proven in R7
        k_attn_d<<<dim3(8, 4, 16), 256, 0, stream>>>(qws, kws, vtws, ows, mpart, lsumf);
        k_mean_combine_linv<<<2048, 256, 0, stream>>>(mpart, lsumf, d_out, flag);
    } else {
        int ng = (ws_size >= 102769152ull) ? 8 : 4;
        k_attn<false><<<dim3(64, 4, ng), 256, 0, stream>>>(qws, kws, vtws, ows, mpart, lsumf, 16 / ng);
        k_mean_combine<<<2048, 256, 0, stream>>>(mpart, d_out, flag, ng);
    }
    k_gemm_out<<<dim3(32, 8), 256, 0, stream>>>(ows, w_outT, b_outb, d_out, flag);
}

// Round 10
// 210.020 us; speedup vs baseline: 1.1485x; 1.1485x over previous
//
#include <hip/hip_runtime.h>

typedef __attribute__((ext_vector_type(8))) short bf16x8;   // 8 bf16 = 4 VGPRs
typedef __attribute__((ext_vector_type(4))) float f32x4;

#define MFMA16(a, b, c) __builtin_amdgcn_mfma_f32_16x16x32_bf16((a), (b), (c), 0, 0, 0)

__device__ __forceinline__ float bf2f(unsigned short h) {
    union { unsigned int u; float f; } v; v.u = ((unsigned int)h) << 16; return v.f;
}
__device__ __forceinline__ unsigned short f2bf(float f) {
    union { float f; unsigned int u; } v; v.f = f;
    unsigned int u = v.u;
    return (unsigned short)((u + 0x7fffu + ((u >> 16) & 1u)) >> 16);  // RNE
}

// Async global->LDS, 16B per lane (wave-uniform base + lane*16 layout).
__device__ __forceinline__ void gload16(const void* g, void* l) {
    __builtin_amdgcn_global_load_lds(
        (const __attribute__((address_space(1))) unsigned int*)(unsigned long long)g,
        (__attribute__((address_space(3))) unsigned int*)(unsigned int)(unsigned long long)l,
        16, 0, 0);
}

// ---------------------------------------------------------------------------
// Dtype probe: flag=1 -> fp32 buffers, 0 -> bf16. (R2/R3/R6/R7 confirmed fp32.)
// ---------------------------------------------------------------------------
__global__ void k_probe(const unsigned int* __restrict__ x, int* __restrict__ flag) {
    int lane = threadIdx.x;                     // 64 threads
    unsigned int bad = 0;
#pragma unroll
    for (int i = 0; i < 4; ++i) {
        unsigned int u = x[lane + 64 * i];
        unsigned int e = (u >> 7) & 0xFFu;
        if (e >= 0x90u) bad = 1;
    }
    unsigned long long m = __ballot(bad != 0);
    if (lane == 0) *flag = (m != 0ull) ? 1 : 0;
}

// ---------------------------------------------------------------------------
// Convert x, b_in, b_out into bf16 staging (contiguous).
// ---------------------------------------------------------------------------
__global__ __launch_bounds__(256) void k_convert(const void* __restrict__ x,
        const void* __restrict__ b_in, const void* __restrict__ b_out,
        unsigned short* __restrict__ dst, const int* __restrict__ flag)
{
    const int isf = *flag;
    const long long N0 = 4194304, N1 = N0 + 3072, N2 = N1 + 1024;
    long long stride = (long long)gridDim.x * 256;
    for (long long idx = (long long)blockIdx.x * 256 + threadIdx.x; idx < N2; idx += stride) {
        const void* src; long long off;
        if (idx < N0)      { src = x;     off = idx; }
        else if (idx < N1) { src = b_in;  off = idx - N0; }
        else               { src = b_out; off = idx - N1; }
        dst[idx] = isf ? f2bf(((const float*)src)[off])
                       : ((const unsigned short*)src)[off];
    }
}

// ---------------------------------------------------------------------------
// Transpose src[K][N] -> dst[N][K] bf16. 64x64 tiles, full coverage.
// ---------------------------------------------------------------------------
__global__ __launch_bounds__(256) void k_transpose(const void* __restrict__ src,
        unsigned short* __restrict__ dst, int K, int N, const int* __restrict__ flag)
{
    __shared__ unsigned short ls[64][72];
    const int isf = *flag;
    const int tid = threadIdx.x;
    const int n0 = blockIdx.x * 64, k0 = blockIdx.y * 64;
    const int r = tid >> 2, c = (tid & 3) * 16;
    union { uint4 v[2]; unsigned short s[16]; } p;
    if (isf) {
        const float* s = (const float*)src + (long long)(k0 + r) * N + n0 + c;
#pragma unroll
        for (int q4 = 0; q4 < 4; ++q4) {
            float4 f = *(const float4*)(s + q4 * 4);
            p.s[q4 * 4 + 0] = f2bf(f.x); p.s[q4 * 4 + 1] = f2bf(f.y);
            p.s[q4 * 4 + 2] = f2bf(f.z); p.s[q4 * 4 + 3] = f2bf(f.w);
        }
    } else {
        const unsigned short* s = (const unsigned short*)src + (long long)(k0 + r) * N + n0 + c;
        p.v[0] = *(const uint4*)s;
        p.v[1] = *(const uint4*)(s + 8);
    }
    *(uint4*)&ls[r][c]     = p.v[0];
    *(uint4*)&ls[r][c + 8] = p.v[1];
    __syncthreads();
    union { uint4 v[2]; unsigned short s[16]; } q;
#pragma unroll
    for (int j = 0; j < 16; ++j) q.s[j] = ls[c + j][r];
    unsigned short* d = dst + (long long)(n0 + r) * K + k0 + c;
    *(uint4*)d = q.v[0];
    *(uint4*)(d + 8) = q.v[1];
}

// ---------------------------------------------------------------------------
// 128x128 GEMM core (m97 structure): C = A[128xK] * BT[128xK]^T, bf16/fp32acc.
// global_load_lds width-16 staging, BK=32, 2 barriers/iter.
// ---------------------------------------------------------------------------
__device__ __forceinline__ void gemm_core(const unsigned short* A, int lda,
        const unsigned short* BT, int ldb, int K,
        unsigned short* lA, unsigned short* lB, f32x4 acc[4][4])
{
    const int tid = threadIdx.x;
    const int w = tid >> 6, wr = w >> 1, wc = w & 1;
    const int lane = tid & 63, quad = lane >> 4, li = lane & 15;
    const int sr = tid >> 2, sk = (tid & 3) * 8;
    const unsigned short* ag = A + (long long)sr * lda + sk;
    const unsigned short* bg = BT + (long long)sr * ldb + sk;
    for (int k0 = 0; k0 < K; k0 += 32) {
        gload16(ag,            lA + tid * 8);
        gload16(ag + 64 * lda, lA + 2048 + tid * 8);
        gload16(bg,            lB + tid * 8);
        gload16(bg + 64 * ldb, lB + 2048 + tid * 8);
        ag += 32; bg += 32;
        __syncthreads();                       // drains vmcnt (compiler-inserted)
        bf16x8 af[4], bfr[4];
#pragma unroll
        for (int i = 0; i < 4; ++i) {
            af[i]  = *(const bf16x8*)(lA + (wr * 64 + i * 16 + li) * 32 + quad * 8);
            bfr[i] = *(const bf16x8*)(lB + (wc * 64 + i * 16 + li) * 32 + quad * 8);
        }
#pragma unroll
        for (int at = 0; at < 4; ++at)
#pragma unroll
            for (int bt = 0; bt < 4; ++bt)
                acc[at][bt] = MFMA16(af[at], bfr[bt], acc[at][bt]);
        __syncthreads();                       // reads done before next staging
    }
}

// ---------------------------------------------------------------------------
// QKV projection: 128x128 tiles, grid (32, 24).
// ---------------------------------------------------------------------------
__global__ __launch_bounds__(256) void k_gemm_qkv(const unsigned short* __restrict__ x,
        const unsigned short* __restrict__ w_inT, const unsigned short* __restrict__ b_in,
        unsigned short* __restrict__ qws, unsigned short* __restrict__ kws,
        unsigned short* __restrict__ vtws)
{
    __shared__ unsigned short sm[17408];                 // lA|lB staging, then lC
    unsigned short (*lC)[136] = (unsigned short (*)[136])sm;
    const int gm0 = blockIdx.x * 128, gn0 = blockIdx.y * 128;
    f32x4 acc[4][4];
#pragma unroll
    for (int i = 0; i < 4; ++i)
#pragma unroll
        for (int j = 0; j < 4; ++j) acc[i][j] = (f32x4){0.f, 0.f, 0.f, 0.f};
    gemm_core(x + (long long)gm0 * 1024, 1024, w_inT + (long long)gn0 * 1024, 1024, 1024,
              sm, sm + 4096, acc);

    const int tid = threadIdx.x, w = tid >> 6, wr = w >> 1, wc = w & 1;
    const int lane = tid & 63, quad = lane >> 4, li = lane & 15;
    const float qscale = (gn0 < 1024) ? 0.03125f : 1.0f;
#pragma unroll
    for (int at = 0; at < 4; ++at)
#pragma unroll
        for (int bt = 0; bt < 4; ++bt)
#pragma unroll
            for (int r = 0; r < 4; ++r) {
                int row = wr * 64 + at * 16 + quad * 4 + r;
                int col = wc * 64 + bt * 16 + li;
                lC[row][col] = f2bf((acc[at][bt][r] + bf2f(b_in[gn0 + col])) * qscale);
            }
    __syncthreads();
    const int region = gn0 >> 10, h0 = (gn0 & 1023) >> 6, b = gm0 >> 10, s0 = gm0 & 1023;
    if (region < 2) {                                    // q or k
        unsigned short* base = (region == 0 ? qws : kws);
        int mm = tid >> 1, hh = tid & 1;
        unsigned short* dst = base + ((long long)(b * 16 + h0 + hh) * 1024 + s0 + mm) * 64;
#pragma unroll
        for (int j = 0; j < 8; ++j)
            *(uint4*)(dst + j * 8) = *(const uint4*)&lC[mm][hh * 64 + j * 8];
    } else {                                             // v transposed
        int d = tid >> 2, sub = tid & 3, hh = sub >> 1, cs = (sub & 1) * 64;
        unsigned short* dst = vtws + ((long long)(b * 16 + h0 + hh) * 64 + d) * 1024 + s0 + cs;
#pragma unroll
        for (int j8 = 0; j8 < 8; ++j8) {
            union { uint4 v; unsigned short s[8]; } p;
#pragma unroll
            for (int i = 0; i < 8; ++i) p.s[i] = lC[cs + j8 * 8 + i][hh * 64 + d];
            *(uint4*)(dst + j8 * 8) = p.v;
        }
    }
}

// ---------------------------------------------------------------------------
// DIRECT attention, R17 = R15/R8 verbatim (proven 41.8 us): LDS-staged K/V
// shared by 4 waves, single-buffered (64KB -> 2 blocks/CU; R9 proved the
// dbuf's 96KB/1-block variant loses inter-block overlap and regresses 2x).
// Block = 4 waves x 32 q-rows = 128 q, one head; per k-chunk of 128: stage
// K(16KB)+V(16KB) via contiguous global_load_lds (source pre-swizzled,
// ds_read same XOR -> conflict-free). Fused unnormalized mpart store;
// linvg reciprocals; direct ows. Grid (8,4,16) x 256 thr; XCD swizzle.
// ---------------------------------------------------------------------------
__global__ __launch_bounds__(256, 2)
void k_attn_d(const unsigned short* __restrict__ qw,
        const unsigned short* __restrict__ kw, const unsigned short* __restrict__ vtw,
        unsigned short* __restrict__ ows, unsigned short* __restrict__ mpart,
        float* __restrict__ linvg)
{
    __shared__ unsigned short lK[8192];           // 128 k-rows x 64 d, swizzled
    __shared__ unsigned short lV[8192];           // 64 d-rows x 128 s, swizzled
    __shared__ unsigned short P[4][8][32][16];    // per-wave P, 8KB each

    const int lin = blockIdx.x + (blockIdx.y << 3) + (blockIdx.z << 5);
    const int work = (lin >> 3) + ((lin & 7) << 6);       // bijective: 512 = 8*64
    const int qt = work & 7, u = work >> 3;               // u = b*16+h, 0..63
    const int tid = threadIdx.x, w = tid >> 6, lane = tid & 63;
    const int quad = lane >> 4, li = lane & 15;
    const int q0w = qt * 128 + w * 32;
    const int h = u & 15, brow = (u >> 4) * 1024;
    unsigned short (*Pw)[32][16] = P[w];

    const unsigned short* qb = qw + ((long long)u * 1024 + q0w + li) * 64 + quad * 8;
    bf16x8 qA0 = *(const bf16x8*)qb;              // q-half A: rows q0w+li
    bf16x8 qA1 = *(const bf16x8*)(qb + 32);
    bf16x8 qB0 = *(const bf16x8*)(qb + 1024);     // q-half B: rows q0w+16+li
    bf16x8 qB1 = *(const bf16x8*)(qb + 1024 + 32);

    const unsigned short* kbh = kw + (long long)u * 65536;
    const unsigned short* vbh = vtw + (long long)u * 65536;
    unsigned short* mp = mpart + ((long long)h << 22);
    const long long rowoffA = (long long)(brow + q0w + li) * 1024;
    const long long rowoffB = rowoffA + 16 * 1024;

    float rsA[4] = {0.f, 0.f, 0.f, 0.f}, rsB[4] = {0.f, 0.f, 0.f, 0.f};
    f32x4 oaccA[4] = {{0,0,0,0},{0,0,0,0},{0,0,0,0},{0,0,0,0}};
    f32x4 oaccB[4] = {{0,0,0,0},{0,0,0,0},{0,0,0,0},{0,0,0,0}};

    for (int c = 0; c < 8; ++c) {
        // ---- stage K,V chunk: contiguous gload16, source pre-swizzled.
        //      K slot t (16B units): r=t>>3, holds global chunk (t&7)^(r&7).
        //      V slot t: d=t>>4, holds global chunk (t&15)^(d&15).
#pragma unroll
        for (int p = 0; p < 4; ++p) {
            int t = p * 256 + tid;
            int kr = t >> 3, kcg = (t & 7) ^ (kr & 7);
            gload16(kbh + c * 8192 + kr * 64 + kcg * 8, lK + t * 8);
            int vd = t >> 4, vcg = (t & 15) ^ (vd & 15);
            gload16(vbh + vd * 1024 + c * 128 + vcg * 8, lV + t * 8);
        }
        __syncthreads();                          // vmcnt drained by compiler
        // ---- score: 8 kt tiles -> 2 q-halves -> exp -> P (own-wave LDS) ----
#pragma unroll
        for (int kt = 0; kt < 8; ++kt) {
            int b16 = (kt * 16 + li) * 8 + (quad ^ (li & 7));   // swizzled slot
            bf16x8 kf0 = *(const bf16x8*)(lK + b16 * 8);
            bf16x8 kf1 = *(const bf16x8*)(lK + (b16 ^ 4) * 8);  // chunk+4
            f32x4 a = {0.f, 0.f, 0.f, 0.f};
            a = MFMA16(qA0, kf0, a);
            a = MFMA16(qA1, kf1, a);
            f32x4 a2 = {0.f, 0.f, 0.f, 0.f};
            a2 = MFMA16(qB0, kf0, a2);
            a2 = MFMA16(qB1, kf1, a2);
#pragma unroll
            for (int r = 0; r < 4; ++r) {
                float p = __expf(a[r]);
                rsA[r] += p;
                Pw[kt][quad * 4 + r][li] = f2bf(p);
                float p2 = __expf(a2[r]);
                rsB[r] += p2;
                Pw[kt][16 + quad * 4 + r][li] = f2bf(p2);
            }
        }
        // ---- PV on unnormalized P + fused mpart store; V via swizzled LDS ----
#pragma unroll
        for (int t = 0; t < 4; ++t) {
            union { bf16x8 v; uint4 u4; } paA, paB;
            paA.v = *(const bf16x8*)&Pw[2 * t + (quad >> 1)][li][(quad & 1) * 8];
            paB.v = *(const bf16x8*)&Pw[2 * t + (quad >> 1)][16 + li][(quad & 1) * 8];
            *(uint4*)(mp + rowoffA + c * 128 + t * 32 + quad * 8) = paA.u4;
            *(uint4*)(mp + rowoffB + c * 128 + t * 32 + quad * 8) = paB.u4;
#pragma unroll
            for (int nt = 0; nt < 4; ++nt) {
                int idx = (nt * 16 + li) * 16 + ((t * 4 + quad) ^ li);
                bf16x8 vf = *(const bf16x8*)(lV + idx * 8);
                oaccA[nt] = MFMA16(paA.v, vf, oaccA[nt]);
                oaccB[nt] = MFMA16(paB.v, vf, oaccB[nt]);
            }
        }
        __syncthreads();                          // LDS reads done before restage
    }
    // ---- complete row sums: shuffle-reduce over li (k-cols; within quad) ----
#pragma unroll
    for (int r = 0; r < 4; ++r) {
        float sA = rsA[r], sB = rsB[r];
#pragma unroll
        for (int d = 1; d < 16; d <<= 1) { sA += __shfl_xor(sA, d, 64); sB += __shfl_xor(sB, d, 64); }
        rsA[r] = 1.f / sA;
        rsB[r] = 1.f / sB;
    }
    if (li == 0) {
        float* lg = linvg + ((long long)h << 12) + brow + q0w + quad * 4;
#pragma unroll
        for (int r = 0; r < 4; ++r) { lg[r] = rsA[r]; lg[16 + r] = rsB[r]; }
    }
    // ---- direct ows store: q = (qh*16)+quad*4+r, d = nt*16+li ----
    unsigned short* ob = ows + (long long)(brow + q0w) * 1024 + h * 64;
#pragma unroll
    for (int r = 0; r < 4; ++r) {
#pragma unroll
        for (int nt = 0; nt < 4; ++nt) {
            ob[(quad * 4 + r) * 1024 + nt * 16 + li]      = f2bf(oaccA[nt][r] * rsA[r]);
            ob[(16 + quad * 4 + r) * 1024 + nt * 16 + li] = f2bf(oaccB[nt][r] * rsB[r]);
        }
    }
}

// ---------------------------------------------------------------------------
// DIRECT combine: 16 UNNORMALIZED planes x linv[g][row] (reciprocal already
// computed by attn), then x 1/16.
// ---------------------------------------------------------------------------
__global__ __launch_bounds__(256) void k_mean_combine_linv(const unsigned short* __restrict__ mp,
        const float* __restrict__ linvg, void* __restrict__ dout, const int* __restrict__ flag)
{
    const int isf = *flag;
    long long idx = ((long long)blockIdx.x * 256 + threadIdx.x) * 8;
    const int row = (int)(idx >> 10);             // b*1024 + q, 0..4095
    float o[8] = {0, 0, 0, 0, 0, 0, 0, 0};
    for (int g = 0; g < 16; ++g) {
        float linv = linvg[((long long)g << 12) + row];
        union { uint4 v; unsigned short s[8]; } p;
        p.v = *(const uint4*)(mp + ((long long)g << 22) + idx);
#pragma unroll
        for (int j = 0; j < 8; ++j) o[j] += bf2f(p.s[j]) * linv;
    }
#pragma unroll
    for (int j = 0; j < 8; ++j) o[j] *= 0.0625f;
    if (isf) {
        float* dst = (float*)dout + 4194304 + idx;
        float4 a = {o[0], o[1], o[2], o[3]}, bq = {o[4], o[5], o[6], o[7]};
        *(float4*)dst = a;
        *(float4*)(dst + 4) = bq;
    } else {
        union { uint4 v; unsigned short s[8]; } pk;
#pragma unroll
        for (int j = 0; j < 8; ++j) pk.s[j] = f2bf(o[j]);
        *(uint4*)((unsigned short*)dout + 4194304 + idx) = pk.v;
    }
}

// ---------------------------------------------------------------------------
// FUSED epilogue (tier-1, linv in ws): blocks 0..255 = output projection
// (128x128 tile, bx=id&31, by=id>>5), blocks 256..2303 = mean combine.
// The two roles touch disjoint memory (ows/w_outT -> out region vs
// mpart/linv -> attn_mean region), so they overlap on the machine instead
// of serializing as two launches. gemm blocks scheduled first (low ids).
// ---------------------------------------------------------------------------
__global__ __launch_bounds__(256) void k_out_fused(const unsigned short* __restrict__ aws,
        const unsigned short* __restrict__ w_outT, const unsigned short* __restrict__ b_out,
        const unsigned short* __restrict__ mp, const float* __restrict__ linvg,
        void* __restrict__ dout, const int* __restrict__ flag)
{
    const int isf = *flag;
    if (blockIdx.x < 256) {
        // ---- gemm_out role ----
        __shared__ unsigned short sm[17408];
        unsigned short (*lC)[136] = (unsigned short (*)[136])sm;
        const int gm0 = (blockIdx.x & 31) * 128, gn0 = (blockIdx.x >> 5) * 128;
        f32x4 acc[4][4];
#pragma unroll
        for (int i = 0; i < 4; ++i)
#pragma unroll
            for (int j = 0; j < 4; ++j) acc[i][j] = (f32x4){0.f, 0.f, 0.f, 0.f};
        gemm_core(aws + (long long)gm0 * 1024, 1024, w_outT + (long long)gn0 * 1024, 1024, 1024,
                  sm, sm + 4096, acc);

        const int tid = threadIdx.x, w = tid >> 6, wr = w >> 1, wc = w & 1;
        const int lane = tid & 63, quad = lane >> 4, li = lane & 15;
#pragma unroll
        for (int at = 0; at < 4; ++at)
#pragma unroll
            for (int bt = 0; bt < 4; ++bt)
#pragma unroll
                for (int r = 0; r < 4; ++r) {
                    int row = wr * 64 + at * 16 + quad * 4 + r;
                    int col = wc * 64 + bt * 16 + li;
                    lC[row][col] = f2bf(acc[at][bt][r] + bf2f(b_out[gn0 + col]));
                }
        __syncthreads();
        int mm = tid >> 1, ch = (tid & 1) * 64;
        if (isf) {
            float* dst = (float*)dout + (long long)(gm0 + mm) * 1024 + gn0 + ch;
#pragma unroll
            for (int j4 = 0; j4 < 16; ++j4) {
                float4 f;
                f.x = bf2f(lC[mm][ch + j4 * 4 + 0]);
                f.y = bf2f(lC[mm][ch + j4 * 4 + 1]);
                f.z = bf2f(lC[mm][ch + j4 * 4 + 2]);
                f.w = bf2f(lC[mm][ch + j4 * 4 + 3]);
                *(float4*)(dst + j4 * 4) = f;
            }
        } else {
            unsigned short* dst = (unsigned short*)dout + (long long)(gm0 + mm) * 1024 + gn0 + ch;
#pragma unroll
            for (int j = 0; j < 8; ++j)
                *(uint4*)(dst + j * 8) = *(const uint4*)&lC[mm][ch + j * 8];
        }
    } else {
        // ---- combine role ----
        long long idx = ((long long)(blockIdx.x - 256) * 256 + threadIdx.x) * 8;
        const int row = (int)(idx >> 10);         // b*1024 + q, 0..4095
        float o[8] = {0, 0, 0, 0, 0, 0, 0, 0};
        for (int g = 0; g < 16; ++g) {
            float linv = linvg[((long long)g << 12) + row];
            union { uint4 v; unsigned short s[8]; } p;
            p.v = *(const uint4*)(mp + ((long long)g << 22) + idx);
#pragma unroll
            for (int j = 0; j < 8; ++j) o[j] += bf2f(p.s[j]) * linv;
        }
#pragma unroll
        for (int j = 0; j < 8; ++j) o[j] *= 0.0625f;
        if (isf) {
            float* dst = (float*)dout + 4194304 + idx;
            float4 a = {o[0], o[1], o[2], o[3]}, bq = {o[4], o[5], o[6], o[7]};
            *(float4*)dst = a;
            *(float4*)(dst + 4) = bq;
        } else {
            union { uint4 v; unsigned short s[8]; } pk;
#pragma unroll
            for (int j = 0; j < 8; ++j) pk.s[j] = f2bf(o[j]);
            *(uint4*)((unsigned short*)dout + 4194304 + idx) = pk.v;
        }
    }
}

// ---------------------------------------------------------------------------
// Fallback fused attention (non-DIRECT ws sizes), unchanged from R7.
// ---------------------------------------------------------------------------
template<bool DIRECT>
__global__ __launch_bounds__(256, DIRECT ? 4 : 2)
void k_attn(const unsigned short* __restrict__ qw,
        const unsigned short* __restrict__ kw, const unsigned short* __restrict__ vtw,
        unsigned short* __restrict__ ows, unsigned short* __restrict__ mpart,
        float* __restrict__ lsumg, int hpg)
{
    __shared__ unsigned short P[4][16][16][16];   // 32 KB, per-wave [kt][row][col16]
    __shared__ float red[4][16];
    float (*obuf)[16][65] = (float (*)[16][65])&P[0][0][0][0];   // alias, used late
    const int b = blockIdx.y, q0 = blockIdx.x * 16, g = blockIdx.z;
    const int tid = threadIdx.x, w = tid >> 6, lane = tid & 63, quad = lane >> 4, li = lane & 15;

    float mean_acc[DIRECT ? 1 : 64];
    if constexpr (!DIRECT) {
#pragma unroll
        for (int i = 0; i < 64; ++i) mean_acc[i] = 0.f;
    }

    for (int hh = 0; hh < hpg; ++hh) {
        const int h = g * hpg + hh;
        const unsigned short* qb = qw + ((long long)(b * 16 + h) * 1024 + q0 + li) * 64 + quad * 8;
        bf16x8 qf0 = *(const bf16x8*)qb;
        bf16x8 qf1 = *(const bf16x8*)(qb + 32);

        // ---- score pass: MFMA -> exp -> P(LDS) + row-sum ----
        float rsum[4] = {0.f, 0.f, 0.f, 0.f};
        const unsigned short* kbh = kw + (long long)(b * 16 + h) * 65536;
#pragma unroll
        for (int kt = 0; kt < 16; ++kt) {
            const unsigned short* kb = kbh + (w * 256 + kt * 16 + li) * 64 + quad * 8;
            bf16x8 kf0 = *(const bf16x8*)kb;
            bf16x8 kf1 = *(const bf16x8*)(kb + 32);
            f32x4 a = {0.f, 0.f, 0.f, 0.f};
            a = MFMA16(qf0, kf0, a);
            a = MFMA16(qf1, kf1, a);
#pragma unroll
            for (int r = 0; r < 4; ++r) {
                float p = __expf(a[r]);
                rsum[r] += p;
                P[w][kt][quad * 4 + r][li] = f2bf(p);
            }
        }
#pragma unroll
        for (int r = 0; r < 4; ++r) {
            float s = rsum[r];
#pragma unroll
            for (int d = 1; d < 16; d <<= 1) s += __shfl_xor(s, d, 64);
            rsum[r] = s;
        }
        if (li == 0) {
#pragma unroll
            for (int r = 0; r < 4; ++r) red[w][quad * 4 + r] = rsum[r];
        }
        // ---- PV on UNNORMALIZED P (own-wave LDS, pre-barrier) ----
        f32x4 oacc[4] = {{0,0,0,0},{0,0,0,0},{0,0,0,0},{0,0,0,0}};
        const unsigned short* vbh = vtw + (long long)(b * 16 + h) * 65536;
        unsigned short* mp = mpart + ((long long)h << 22);
        const long long rowoff2 = (long long)(b * 1024 + q0 + li) * 1024 + w * 256;
#pragma unroll
        for (int t = 0; t < 8; ++t) {
            union { bf16x8 v; uint4 u; } pa;
            pa.v = *(const bf16x8*)&P[w][2 * t + (quad >> 1)][li][(quad & 1) * 8];
            if constexpr (DIRECT)
                *(uint4*)(mp + rowoff2 + t * 32 + quad * 8) = pa.u;
            const int sv0 = w * 256 + t * 32;
#pragma unroll
            for (int nt = 0; nt < 4; ++nt) {
                const unsigned short* vb = vbh + (nt * 16 + li) * 1024 + sv0 + quad * 8;
                bf16x8 vf = *(const bf16x8*)vb;
                oacc[nt] = MFMA16(pa.v, vf, oacc[nt]);
            }
        }
        __syncthreads();                          // red ready AND all P reads done
        float linv[4];
#pragma unroll
        for (int r = 0; r < 4; ++r)
            linv[r] = 1.f / (red[0][quad * 4 + r] + red[1][quad * 4 + r] +
                             red[2][quad * 4 + r] + red[3][quad * 4 + r]);
        if constexpr (DIRECT) {
            if (tid < 16) {
                float s = red[0][tid] + red[1][tid] + red[2][tid] + red[3][tid];
                lsumg[((long long)h << 12) + b * 1024 + q0 + tid] = s;
            }
        } else {
            float lrow = 1.f / (red[0][li] + red[1][li] + red[2][li] + red[3][li]);
#pragma unroll
            for (int t = 0; t < 8; ++t) {
                union { bf16x8 v; unsigned short s[8]; } pa;
                pa.v = *(const bf16x8*)&P[w][2 * t + (quad >> 1)][li][(quad & 1) * 8];
#pragma unroll
                for (int j = 0; j < 8; ++j) mean_acc[t * 8 + j] += bf2f(pa.s[j]) * lrow;
            }
            __syncthreads();                      // all P reads done before obuf alias
        }
#pragma unroll
        for (int nt = 0; nt < 4; ++nt)
#pragma unroll
            for (int r = 0; r < 4; ++r)
                obuf[w][quad * 4 + r][nt * 16 + li] = oacc[nt][r] * linv[r];
        __syncthreads();
        {
            int row = tid >> 4, c4 = (tid & 15) * 4;
            union { uint2 v2; unsigned short s[4]; } pk;
#pragma unroll
            for (int j = 0; j < 4; ++j) {
                float s = obuf[0][row][c4 + j] + obuf[1][row][c4 + j] +
                          obuf[2][row][c4 + j] + obuf[3][row][c4 + j];
                pk.s[j] = f2bf(s);
            }
            *(uint2*)(ows + ((long long)(b * 1024) + q0 + row) * 1024 + h * 64 + c4) = pk.v2;
        }
        if (hh + 1 < hpg) __syncthreads();        // obuf reads done before next head
    }
    if constexpr (!DIRECT) {
        unsigned short* mp = mpart + ((long long)g << 22);
        long long rowoff2 = (long long)(b * 1024 + q0 + li) * 1024 + w * 256;
#pragma unroll
        for (int t = 0; t < 8; ++t) {
            union { uint4 v; unsigned short s[8]; } u;
#pragma unroll
            for (int j = 0; j < 8; ++j) u.s[j] = f2bf(mean_acc[t * 8 + j]);
            *(uint4*)(mp + rowoff2 + t * 32 + quad * 8) = u.v;
        }
    }
}

// ---------------------------------------------------------------------------
// Fallback combine (normalized partial planes, ng groups), unchanged.
// ---------------------------------------------------------------------------
__global__ __launch_bounds__(256) void k_mean_combine(const unsigned short* __restrict__ mp,
        void* __restrict__ dout, const int* __restrict__ flag, int ng)
{
    const int isf = *flag;
    long long idx = ((long long)blockIdx.x * 256 + threadIdx.x) * 8;
    float o[8] = {0, 0, 0, 0, 0, 0, 0, 0};
    for (int g = 0; g < ng; ++g) {
        union { uint4 v; unsigned short s[8]; } p;
        p.v = *(const uint4*)(mp + ((long long)g << 22) + idx);
#pragma unroll
        for (int j = 0; j < 8; ++j) o[j] += bf2f(p.s[j]);
    }
#pragma unroll
    for (int j = 0; j < 8; ++j) o[j] *= 0.0625f;
    if (isf) {
        float* dst = (float*)dout + 4194304 + idx;
        float4 a = {o[0], o[1], o[2], o[3]}, bq = {o[4], o[5], o[6], o[7]};
        *(float4*)dst = a;
        *(float4*)(dst + 4) = bq;
    } else {
        union { uint4 v; unsigned short s[8]; } pk;
#pragma unroll
        for (int j = 0; j < 8; ++j) pk.s[j] = f2bf(o[j]);
        *(uint4*)((unsigned short*)dout + 4194304 + idx) = pk.v;
    }
}

// ---------------------------------------------------------------------------
// Output projection: 128x128 tiles, grid (32, 8). (tier-2 / fallback path)
// ---------------------------------------------------------------------------
__global__ __launch_bounds__(256) void k_gemm_out(const unsigned short* __restrict__ aws,
        const unsigned short* __restrict__ w_outT, const unsigned short* __restrict__ b_out,
        void* __restrict__ dout, const int* __restrict__ flag)
{
    __shared__ unsigned short sm[17408];
    unsigned short (*lC)[136] = (unsigned short (*)[136])sm;
    const int gm0 = blockIdx.x * 128, gn0 = blockIdx.y * 128;
    const int isf = *flag;
    f32x4 acc[4][4];
#pragma unroll
    for (int i = 0; i < 4; ++i)
#pragma unroll
        for (int j = 0; j < 4; ++j) acc[i][j] = (f32x4){0.f, 0.f, 0.f, 0.f};
    gemm_core(aws + (long long)gm0 * 1024, 1024, w_outT + (long long)gn0 * 1024, 1024, 1024,
              sm, sm + 4096, acc);

    const int tid = threadIdx.x, w = tid >> 6, wr = w >> 1, wc = w & 1;
    const int lane = tid & 63, quad = lane >> 4, li = lane & 15;
#pragma unroll
    for (int at = 0; at < 4; ++at)
#pragma unroll
        for (int bt = 0; bt < 4; ++bt)
#pragma unroll
            for (int r = 0; r < 4; ++r) {
                int row = wr * 64 + at * 16 + quad * 4 + r;
                int col = wc * 64 + bt * 16 + li;
                lC[row][col] = f2bf(acc[at][bt][r] + bf2f(b_out[gn0 + col]));
            }
    __syncthreads();
    int mm = tid >> 1, ch = (tid & 1) * 64;
    if (isf) {
        float* dst = (float*)dout + (long long)(gm0 + mm) * 1024 + gn0 + ch;
#pragma unroll
        for (int j4 = 0; j4 < 16; ++j4) {
            float4 f;
            f.x = bf2f(lC[mm][ch + j4 * 4 + 0]);
            f.y = bf2f(lC[mm][ch + j4 * 4 + 1]);
            f.z = bf2f(lC[mm][ch + j4 * 4 + 2]);
            f.w = bf2f(lC[mm][ch + j4 * 4 + 3]);
            *(float4*)(dst + j4 * 4) = f;
        }
    } else {
        unsigned short* dst = (unsigned short*)dout + (long long)(gm0 + mm) * 1024 + gn0 + ch;
#pragma unroll
        for (int j = 0; j < 8; ++j)
            *(uint4*)(dst + j * 8) = *(const uint4*)&lC[mm][ch + j * 8];
    }
}

// ---------------------------------------------------------------------------
// ws layout (shorts): [flag 256][xb/ows 4.19M][b_in 3072][b_out 1024]
// [w_outT 1.05M][qws 4.19M][kws 4.19M][vtws 4.19M][w_inT 3.15M | mpart 16 x
// 4.19M (alias)]. mpart ends at short 84,939,008 = byte 169,878,016 (the
// proven DIRECT threshold). Tier-1 (ws_size >= 170,140,160): linv (64K fp32,
// 256KB) lives AFTER mpart in ws -> combine and gemm_out fuse into one
// overlapped launch. Tier-2: linv at start of d_out (dead until gemm_out),
// separate launches exactly as R8. Fallback: ng-group path.
// ---------------------------------------------------------------------------
extern "C" void kernel_launch(void* const* d_in, const int* in_sizes, int n_in,
                              void* d_out, int out_size, void* d_ws, size_t ws_size,
                              hipStream_t stream)
{
    int* flag = (int*)d_ws;
    unsigned short* xb     = (unsigned short*)d_ws + 256;      // 4,194,304
    unsigned short* b_inb  = xb + 4194304;                     // 3,072
    unsigned short* b_outb = b_inb + 3072;                     // 1,024
    unsigned short* w_outT = b_outb + 1024;                    // 1,048,576
    unsigned short* qws    = w_outT + 1048576;                 // 4,194,304
    unsigned short* kws    = qws + 4194304;                    // 4,194,304
    unsigned short* vtws   = kws + 4194304;                    // 4,194,304
    unsigned short* w_inT  = vtws + 4194304;                   // 3,145,728 (dead after qkv)
    unsigned short* mpart  = w_inT;                            // 16 x 4,194,304 (alias)
    unsigned short* ows    = xb;                               // reuse x staging (dead)
    float* lsumf           = (float*)d_out;                    // tier-2 linv scratch
    float* linv_ws         = (float*)(mpart + 67108864);       // tier-1 linv (after mpart)

    k_probe<<<1, 64, 0, stream>>>((const unsigned int*)d_in[0], flag);
    k_convert<<<4096, 256, 0, stream>>>(d_in[0], d_in[2], d_in[4], xb, flag);
    k_transpose<<<dim3(48, 16), 256, 0, stream>>>(d_in[1], w_inT, 1024, 3072, flag);
    k_transpose<<<dim3(16, 16), 256, 0, stream>>>(d_in[3], w_outT, 1024, 1024, flag);
    k_gemm_qkv<<<dim3(32, 24), 256, 0, stream>>>(xb, w_inT, b_inb, qws, kws, vtws);

    if (ws_size >= 170140160ull) {                             // tier-1: fused epilogue
        k_attn_d<<<dim3(8, 4, 16), 256, 0, stream>>>(qws, kws, vtws, ows, mpart, linv_ws);
        k_out_fused<<<2304, 256, 0, stream>>>(ows, w_outT, b_outb, mpart, linv_ws, d_out, flag);
    } else if (ws_size >= 169878016ull) {                      // tier-2: proven R8 path
        k_attn_d<<<dim3(8, 4, 16), 256, 0, stream>>>(qws, kws, vtws, ows, mpart, lsumf);
        k_mean_combine_linv<<<2048, 256, 0, stream>>>(mpart, lsumf, d_out, flag);
        k_gemm_out<<<dim3(32, 8), 256, 0, stream>>>(ows, w_outT, b_outb, d_out, flag);
    } else {
        int ng = (ws_size >= 102769152ull) ? 8 : 4;
        k_attn<false><<<dim3(64, 4, ng), 256, 0, stream>>>(qws, kws, vtws, ows, mpart, lsumf, 16 / ng);
        k_mean_combine<<<2048, 256, 0, stream>>>(mpart, d_out, flag, ng);
        k_gemm_out<<<dim3(32, 8), 256, 0, stream>>>(ows, w_outT, b_outb, d_out, flag);
    }
}

// Round 11
// 202.981 us; speedup vs baseline: 1.1884x; 1.0347x over previous
//
#include <hip/hip_runtime.h>

typedef __attribute__((ext_vector_type(8))) short bf16x8;   // 8 bf16 = 4 VGPRs
typedef __attribute__((ext_vector_type(4))) float f32x4;

#define MFMA16(a, b, c) __builtin_amdgcn_mfma_f32_16x16x32_bf16((a), (b), (c), 0, 0, 0)

__device__ __forceinline__ float bf2f(unsigned short h) {
    union { unsigned int u; float f; } v; v.u = ((unsigned int)h) << 16; return v.f;
}
__device__ __forceinline__ unsigned short f2bf(float f) {
    union { float f; unsigned int u; } v; v.f = f;
    unsigned int u = v.u;
    return (unsigned short)((u + 0x7fffu + ((u >> 16) & 1u)) >> 16);  // RNE
}

// Async global->LDS, 16B per lane (wave-uniform base + lane*16 layout).
__device__ __forceinline__ void gload16(const void* g, void* l) {
    __builtin_amdgcn_global_load_lds(
        (const __attribute__((address_space(1))) unsigned int*)(unsigned long long)g,
        (__attribute__((address_space(3))) unsigned int*)(unsigned int)(unsigned long long)l,
        16, 0, 0);
}

// ---------------------------------------------------------------------------
// FUSED preamble (R18): probe + convert + both weight transposes in ONE
// launch. Roles by blockIdx.x: [0,768) w_in transpose tiles (48x16),
// [768,1024) w_out transpose tiles (16x16), [1024,3072) x convert (2048
// blocks x 2048 elems, vectorized), 3072 = biases. The dtype probe (same
// bit-logic as the old k_probe, first 256 words of x, L2-resident) runs
// inline in wave 0 of EVERY block and broadcasts via LDS -> no flag
// dependency chain; block 0 persists it for the epilogue kernels.
// ---------------------------------------------------------------------------
__global__ __launch_bounds__(256) void k_prep(const void* __restrict__ x,
        const void* __restrict__ w_in, const void* __restrict__ b_in,
        const void* __restrict__ b_out, const void* __restrict__ w_out,
        unsigned short* __restrict__ xb, unsigned short* __restrict__ w_inT,
        unsigned short* __restrict__ w_outT, int* __restrict__ flagp)
{
    __shared__ unsigned short ls[64][72];
    __shared__ int sflag;
    const int tid = threadIdx.x;
    if (tid < 64) {                               // inline probe, wave 0
        const unsigned int* xw = (const unsigned int*)x;
        unsigned int bad = 0;
#pragma unroll
        for (int i = 0; i < 4; ++i) {
            unsigned int u = xw[tid + 64 * i];
            unsigned int e = (u >> 7) & 0xFFu;
            if (e >= 0x90u) bad = 1;
        }
        unsigned long long m = __ballot(bad != 0);
        if (tid == 0) sflag = (m != 0ull) ? 1 : 0;
    }
    __syncthreads();
    const int isf = sflag;
    const int id = blockIdx.x;
    if (id == 0 && tid == 0) *flagp = isf;

    if (id < 1024) {
        // ---- transpose role: src[K][N] -> dst[N][K], 64x64 tile ----
        const void* src; unsigned short* dst; int N, n0, k0;
        if (id < 768) { src = w_in;  dst = w_inT;  N = 3072; n0 = (id % 48) * 64; k0 = (id / 48) * 64; }
        else { int r2 = id - 768; src = w_out; dst = w_outT; N = 1024; n0 = (r2 & 15) * 64; k0 = (r2 >> 4) * 64; }
        const int K = 1024;
        const int r = tid >> 2, c = (tid & 3) * 16;
        union { uint4 v[2]; unsigned short s[16]; } p;
        if (isf) {
            const float* s = (const float*)src + (long long)(k0 + r) * N + n0 + c;
#pragma unroll
            for (int q4 = 0; q4 < 4; ++q4) {
                float4 f = *(const float4*)(s + q4 * 4);
                p.s[q4 * 4 + 0] = f2bf(f.x); p.s[q4 * 4 + 1] = f2bf(f.y);
                p.s[q4 * 4 + 2] = f2bf(f.z); p.s[q4 * 4 + 3] = f2bf(f.w);
            }
        } else {
            const unsigned short* s = (const unsigned short*)src + (long long)(k0 + r) * N + n0 + c;
            p.v[0] = *(const uint4*)s;
            p.v[1] = *(const uint4*)(s + 8);
        }
        *(uint4*)&ls[r][c]     = p.v[0];
        *(uint4*)&ls[r][c + 8] = p.v[1];
        __syncthreads();
        union { uint4 v[2]; unsigned short s[16]; } q;
#pragma unroll
        for (int j = 0; j < 16; ++j) q.s[j] = ls[c + j][r];
        unsigned short* d = dst + (long long)(n0 + r) * K + k0 + c;
        *(uint4*)d = q.v[0];
        *(uint4*)(d + 8) = q.v[1];
    } else if (id < 3072) {
        // ---- convert-x role: 2048 blocks x 256 thr x 8 elems = 4,194,304 ----
        long long base = (long long)(id - 1024) * 2048 + tid * 8;
        if (isf) {
            const float* s = (const float*)x + base;
            float4 f0 = *(const float4*)s, f1 = *(const float4*)(s + 4);
            union { uint4 v; unsigned short h[8]; } o;
            o.h[0] = f2bf(f0.x); o.h[1] = f2bf(f0.y); o.h[2] = f2bf(f0.z); o.h[3] = f2bf(f0.w);
            o.h[4] = f2bf(f1.x); o.h[5] = f2bf(f1.y); o.h[6] = f2bf(f1.z); o.h[7] = f2bf(f1.w);
            *(uint4*)(xb + base) = o.v;
        } else {
            *(uint4*)(xb + base) = *(const uint4*)((const unsigned short*)x + base);
        }
    } else {
        // ---- bias role: 4096 elems (3072 b_in ++ 1024 b_out) ----
#pragma unroll
        for (int j = 0; j < 16; ++j) {
            int e = tid * 16 + j;
            const void* src = (e < 3072) ? b_in : b_out;
            long long off = (e < 3072) ? e : e - 3072;
            xb[4194304 + e] = isf ? f2bf(((const float*)src)[off])
                                  : ((const unsigned short*)src)[off];
        }
    }
}

// ---------------------------------------------------------------------------
// 128x128 GEMM core (m97 structure): C = A[128xK] * BT[128xK]^T, bf16/fp32acc.
// global_load_lds width-16 staging, BK=32, 2 barriers/iter.
// ---------------------------------------------------------------------------
__device__ __forceinline__ void gemm_core(const unsigned short* A, int lda,
        const unsigned short* BT, int ldb, int K,
        unsigned short* lA, unsigned short* lB, f32x4 acc[4][4])
{
    const int tid = threadIdx.x;
    const int w = tid >> 6, wr = w >> 1, wc = w & 1;
    const int lane = tid & 63, quad = lane >> 4, li = lane & 15;
    const int sr = tid >> 2, sk = (tid & 3) * 8;
    const unsigned short* ag = A + (long long)sr * lda + sk;
    const unsigned short* bg = BT + (long long)sr * ldb + sk;
    for (int k0 = 0; k0 < K; k0 += 32) {
        gload16(ag,            lA + tid * 8);
        gload16(ag + 64 * lda, lA + 2048 + tid * 8);
        gload16(bg,            lB + tid * 8);
        gload16(bg + 64 * ldb, lB + 2048 + tid * 8);
        ag += 32; bg += 32;
        __syncthreads();                       // drains vmcnt (compiler-inserted)
        bf16x8 af[4], bfr[4];
#pragma unroll
        for (int i = 0; i < 4; ++i) {
            af[i]  = *(const bf16x8*)(lA + (wr * 64 + i * 16 + li) * 32 + quad * 8);
            bfr[i] = *(const bf16x8*)(lB + (wc * 64 + i * 16 + li) * 32 + quad * 8);
        }
#pragma unroll
        for (int at = 0; at < 4; ++at)
#pragma unroll
            for (int bt = 0; bt < 4; ++bt)
                acc[at][bt] = MFMA16(af[at], bfr[bt], acc[at][bt]);
        __syncthreads();                       // reads done before next staging
    }
}

// ---------------------------------------------------------------------------
// QKV projection: 128x128 tiles, grid (32, 24).
// ---------------------------------------------------------------------------
__global__ __launch_bounds__(256) void k_gemm_qkv(const unsigned short* __restrict__ x,
        const unsigned short* __restrict__ w_inT, const unsigned short* __restrict__ b_in,
        unsigned short* __restrict__ qws, unsigned short* __restrict__ kws,
        unsigned short* __restrict__ vtws)
{
    __shared__ unsigned short sm[17408];                 // lA|lB staging, then lC
    unsigned short (*lC)[136] = (unsigned short (*)[136])sm;
    const int gm0 = blockIdx.x * 128, gn0 = blockIdx.y * 128;
    f32x4 acc[4][4];
#pragma unroll
    for (int i = 0; i < 4; ++i)
#pragma unroll
        for (int j = 0; j < 4; ++j) acc[i][j] = (f32x4){0.f, 0.f, 0.f, 0.f};
    gemm_core(x + (long long)gm0 * 1024, 1024, w_inT + (long long)gn0 * 1024, 1024, 1024,
              sm, sm + 4096, acc);

    const int tid = threadIdx.x, w = tid >> 6, wr = w >> 1, wc = w & 1;
    const int lane = tid & 63, quad = lane >> 4, li = lane & 15;
    const float qscale = (gn0 < 1024) ? 0.03125f : 1.0f;
#pragma unroll
    for (int at = 0; at < 4; ++at)
#pragma unroll
        for (int bt = 0; bt < 4; ++bt)
#pragma unroll
            for (int r = 0; r < 4; ++r) {
                int row = wr * 64 + at * 16 + quad * 4 + r;
                int col = wc * 64 + bt * 16 + li;
                lC[row][col] = f2bf((acc[at][bt][r] + bf2f(b_in[gn0 + col])) * qscale);
            }
    __syncthreads();
    const int region = gn0 >> 10, h0 = (gn0 & 1023) >> 6, b = gm0 >> 10, s0 = gm0 & 1023;
    if (region < 2) {                                    // q or k
        unsigned short* base = (region == 0 ? qws : kws);
        int mm = tid >> 1, hh = tid & 1;
        unsigned short* dst = base + ((long long)(b * 16 + h0 + hh) * 1024 + s0 + mm) * 64;
#pragma unroll
        for (int j = 0; j < 8; ++j)
            *(uint4*)(dst + j * 8) = *(const uint4*)&lC[mm][hh * 64 + j * 8];
    } else {                                             // v transposed
        int d = tid >> 2, sub = tid & 3, hh = sub >> 1, cs = (sub & 1) * 64;
        unsigned short* dst = vtws + ((long long)(b * 16 + h0 + hh) * 64 + d) * 1024 + s0 + cs;
#pragma unroll
        for (int j8 = 0; j8 < 8; ++j8) {
            union { uint4 v; unsigned short s[8]; } p;
#pragma unroll
            for (int i = 0; i < 8; ++i) p.s[i] = lC[cs + j8 * 8 + i][hh * 64 + d];
            *(uint4*)(dst + j8 * 8) = p.v;
        }
    }
}

// ---------------------------------------------------------------------------
// DIRECT attention = R15/R8 verbatim (proven 41.8 us): LDS-staged K/V shared
// by 4 waves, single-buffered (64KB -> 2 blocks/CU; R9 proved dbuf's 96KB
// variant loses inter-block overlap and regresses 2x). Block = 4 waves x
// 32 q-rows = 128 q, one head; per k-chunk of 128: stage K(16KB)+V(16KB)
// via contiguous global_load_lds (source pre-swizzled, ds_read same XOR ->
// conflict-free). Fused unnormalized mpart store; linvg reciprocals;
// direct ows. Grid (8,4,16) x 256 thr; XCD swizzle.
// ---------------------------------------------------------------------------
__global__ __launch_bounds__(256, 2)
void k_attn_d(const unsigned short* __restrict__ qw,
        const unsigned short* __restrict__ kw, const unsigned short* __restrict__ vtw,
        unsigned short* __restrict__ ows, unsigned short* __restrict__ mpart,
        float* __restrict__ linvg)
{
    __shared__ unsigned short lK[8192];           // 128 k-rows x 64 d, swizzled
    __shared__ unsigned short lV[8192];           // 64 d-rows x 128 s, swizzled
    __shared__ unsigned short P[4][8][32][16];    // per-wave P, 8KB each

    const int lin = blockIdx.x + (blockIdx.y << 3) + (blockIdx.z << 5);
    const int work = (lin >> 3) + ((lin & 7) << 6);       // bijective: 512 = 8*64
    const int qt = work & 7, u = work >> 3;               // u = b*16+h, 0..63
    const int tid = threadIdx.x, w = tid >> 6, lane = tid & 63;
    const int quad = lane >> 4, li = lane & 15;
    const int q0w = qt * 128 + w * 32;
    const int h = u & 15, brow = (u >> 4) * 1024;
    unsigned short (*Pw)[32][16] = P[w];

    const unsigned short* qb = qw + ((long long)u * 1024 + q0w + li) * 64 + quad * 8;
    bf16x8 qA0 = *(const bf16x8*)qb;              // q-half A: rows q0w+li
    bf16x8 qA1 = *(const bf16x8*)(qb + 32);
    bf16x8 qB0 = *(const bf16x8*)(qb + 1024);     // q-half B: rows q0w+16+li
    bf16x8 qB1 = *(const bf16x8*)(qb + 1024 + 32);

    const unsigned short* kbh = kw + (long long)u * 65536;
    const unsigned short* vbh = vtw + (long long)u * 65536;
    unsigned short* mp = mpart + ((long long)h << 22);
    const long long rowoffA = (long long)(brow + q0w + li) * 1024;
    const long long rowoffB = rowoffA + 16 * 1024;

    float rsA[4] = {0.f, 0.f, 0.f, 0.f}, rsB[4] = {0.f, 0.f, 0.f, 0.f};
    f32x4 oaccA[4] = {{0,0,0,0},{0,0,0,0},{0,0,0,0},{0,0,0,0}};
    f32x4 oaccB[4] = {{0,0,0,0},{0,0,0,0},{0,0,0,0},{0,0,0,0}};

    for (int c = 0; c < 8; ++c) {
        // ---- stage K,V chunk: contiguous gload16, source pre-swizzled.
        //      K slot t (16B units): r=t>>3, holds global chunk (t&7)^(r&7).
        //      V slot t: d=t>>4, holds global chunk (t&15)^(d&15).
#pragma unroll
        for (int p = 0; p < 4; ++p) {
            int t = p * 256 + tid;
            int kr = t >> 3, kcg = (t & 7) ^ (kr & 7);
            gload16(kbh + c * 8192 + kr * 64 + kcg * 8, lK + t * 8);
            int vd = t >> 4, vcg = (t & 15) ^ (vd & 15);
            gload16(vbh + vd * 1024 + c * 128 + vcg * 8, lV + t * 8);
        }
        __syncthreads();                          // vmcnt drained by compiler
        // ---- score: 8 kt tiles -> 2 q-halves -> exp -> P (own-wave LDS) ----
#pragma unroll
        for (int kt = 0; kt < 8; ++kt) {
            int b16 = (kt * 16 + li) * 8 + (quad ^ (li & 7));   // swizzled slot
            bf16x8 kf0 = *(const bf16x8*)(lK + b16 * 8);
            bf16x8 kf1 = *(const bf16x8*)(lK + (b16 ^ 4) * 8);  // chunk+4
            f32x4 a = {0.f, 0.f, 0.f, 0.f};
            a = MFMA16(qA0, kf0, a);
            a = MFMA16(qA1, kf1, a);
            f32x4 a2 = {0.f, 0.f, 0.f, 0.f};
            a2 = MFMA16(qB0, kf0, a2);
            a2 = MFMA16(qB1, kf1, a2);
#pragma unroll
            for (int r = 0; r < 4; ++r) {
                float p = __expf(a[r]);
                rsA[r] += p;
                Pw[kt][quad * 4 + r][li] = f2bf(p);
                float p2 = __expf(a2[r]);
                rsB[r] += p2;
                Pw[kt][16 + quad * 4 + r][li] = f2bf(p2);
            }
        }
        // ---- PV on unnormalized P + fused mpart store; V via swizzled LDS ----
#pragma unroll
        for (int t = 0; t < 4; ++t) {
            union { bf16x8 v; uint4 u4; } paA, paB;
            paA.v = *(const bf16x8*)&Pw[2 * t + (quad >> 1)][li][(quad & 1) * 8];
            paB.v = *(const bf16x8*)&Pw[2 * t + (quad >> 1)][16 + li][(quad & 1) * 8];
            *(uint4*)(mp + rowoffA + c * 128 + t * 32 + quad * 8) = paA.u4;
            *(uint4*)(mp + rowoffB + c * 128 + t * 32 + quad * 8) = paB.u4;
#pragma unroll
            for (int nt = 0; nt < 4; ++nt) {
                int idx = (nt * 16 + li) * 16 + ((t * 4 + quad) ^ li);
                bf16x8 vf = *(const bf16x8*)(lV + idx * 8);
                oaccA[nt] = MFMA16(paA.v, vf, oaccA[nt]);
                oaccB[nt] = MFMA16(paB.v, vf, oaccB[nt]);
            }
        }
        __syncthreads();                          // LDS reads done before restage
    }
    // ---- complete row sums: shuffle-reduce over li (k-cols; within quad) ----
#pragma unroll
    for (int r = 0; r < 4; ++r) {
        float sA = rsA[r], sB = rsB[r];
#pragma unroll
        for (int d = 1; d < 16; d <<= 1) { sA += __shfl_xor(sA, d, 64); sB += __shfl_xor(sB, d, 64); }
        rsA[r] = 1.f / sA;
        rsB[r] = 1.f / sB;
    }
    if (li == 0) {
        float* lg = linvg + ((long long)h << 12) + brow + q0w + quad * 4;
#pragma unroll
        for (int r = 0; r < 4; ++r) { lg[r] = rsA[r]; lg[16 + r] = rsB[r]; }
    }
    // ---- direct ows store: q = (qh*16)+quad*4+r, d = nt*16+li ----
    unsigned short* ob = ows + (long long)(brow + q0w) * 1024 + h * 64;
#pragma unroll
    for (int r = 0; r < 4; ++r) {
#pragma unroll
        for (int nt = 0; nt < 4; ++nt) {
            ob[(quad * 4 + r) * 1024 + nt * 16 + li]      = f2bf(oaccA[nt][r] * rsA[r]);
            ob[(16 + quad * 4 + r) * 1024 + nt * 16 + li] = f2bf(oaccB[nt][r] * rsB[r]);
        }
    }
}

// ---------------------------------------------------------------------------
// DIRECT combine: 16 UNNORMALIZED planes x linv[g][row] (reciprocal already
// computed by attn), then x 1/16.
// ---------------------------------------------------------------------------
__global__ __launch_bounds__(256) void k_mean_combine_linv(const unsigned short* __restrict__ mp,
        const float* __restrict__ linvg, void* __restrict__ dout, const int* __restrict__ flag)
{
    const int isf = *flag;
    long long idx = ((long long)blockIdx.x * 256 + threadIdx.x) * 8;
    const int row = (int)(idx >> 10);             // b*1024 + q, 0..4095
    float o[8] = {0, 0, 0, 0, 0, 0, 0, 0};
    for (int g = 0; g < 16; ++g) {
        float linv = linvg[((long long)g << 12) + row];
        union { uint4 v; unsigned short s[8]; } p;
        p.v = *(const uint4*)(mp + ((long long)g << 22) + idx);
#pragma unroll
        for (int j = 0; j < 8; ++j) o[j] += bf2f(p.s[j]) * linv;
    }
#pragma unroll
    for (int j = 0; j < 8; ++j) o[j] *= 0.0625f;
    if (isf) {
        float* dst = (float*)dout + 4194304 + idx;
        float4 a = {o[0], o[1], o[2], o[3]}, bq = {o[4], o[5], o[6], o[7]};
        *(float4*)dst = a;
        *(float4*)(dst + 4) = bq;
    } else {
        union { uint4 v; unsigned short s[8]; } pk;
#pragma unroll
        for (int j = 0; j < 8; ++j) pk.s[j] = f2bf(o[j]);
        *(uint4*)((unsigned short*)dout + 4194304 + idx) = pk.v;
    }
}

// ---------------------------------------------------------------------------
// FUSED epilogue (tier-1, linv in ws): blocks 0..255 = output projection
// (128x128 tile, bx=id&31, by=id>>5), blocks 256..2303 = mean combine.
// Disjoint reads/writes -> the two roles overlap on the machine.
// ---------------------------------------------------------------------------
__global__ __launch_bounds__(256) void k_out_fused(const unsigned short* __restrict__ aws,
        const unsigned short* __restrict__ w_outT, const unsigned short* __restrict__ b_out,
        const unsigned short* __restrict__ mp, const float* __restrict__ linvg,
        void* __restrict__ dout, const int* __restrict__ flag)
{
    const int isf = *flag;
    if (blockIdx.x < 256) {
        // ---- gemm_out role ----
        __shared__ unsigned short sm[17408];
        unsigned short (*lC)[136] = (unsigned short (*)[136])sm;
        const int gm0 = (blockIdx.x & 31) * 128, gn0 = (blockIdx.x >> 5) * 128;
        f32x4 acc[4][4];
#pragma unroll
        for (int i = 0; i < 4; ++i)
#pragma unroll
            for (int j = 0; j < 4; ++j) acc[i][j] = (f32x4){0.f, 0.f, 0.f, 0.f};
        gemm_core(aws + (long long)gm0 * 1024, 1024, w_outT + (long long)gn0 * 1024, 1024, 1024,
                  sm, sm + 4096, acc);

        const int tid = threadIdx.x, w = tid >> 6, wr = w >> 1, wc = w & 1;
        const int lane = tid & 63, quad = lane >> 4, li = lane & 15;
#pragma unroll
        for (int at = 0; at < 4; ++at)
#pragma unroll
            for (int bt = 0; bt < 4; ++bt)
#pragma unroll
                for (int r = 0; r < 4; ++r) {
                    int row = wr * 64 + at * 16 + quad * 4 + r;
                    int col = wc * 64 + bt * 16 + li;
                    lC[row][col] = f2bf(acc[at][bt][r] + bf2f(b_out[gn0 + col]));
                }
        __syncthreads();
        int mm = tid >> 1, ch = (tid & 1) * 64;
        if (isf) {
            float* dst = (float*)dout + (long long)(gm0 + mm) * 1024 + gn0 + ch;
#pragma unroll
            for (int j4 = 0; j4 < 16; ++j4) {
                float4 f;
                f.x = bf2f(lC[mm][ch + j4 * 4 + 0]);
                f.y = bf2f(lC[mm][ch + j4 * 4 + 1]);
                f.z = bf2f(lC[mm][ch + j4 * 4 + 2]);
                f.w = bf2f(lC[mm][ch + j4 * 4 + 3]);
                *(float4*)(dst + j4 * 4) = f;
            }
        } else {
            unsigned short* dst = (unsigned short*)dout + (long long)(gm0 + mm) * 1024 + gn0 + ch;
#pragma unroll
            for (int j = 0; j < 8; ++j)
                *(uint4*)(dst + j * 8) = *(const uint4*)&lC[mm][ch + j * 8];
        }
    } else {
        // ---- combine role ----
        long long idx = ((long long)(blockIdx.x - 256) * 256 + threadIdx.x) * 8;
        const int row = (int)(idx >> 10);         // b*1024 + q, 0..4095
        float o[8] = {0, 0, 0, 0, 0, 0, 0, 0};
        for (int g = 0; g < 16; ++g) {
            float linv = linvg[((long long)g << 12) + row];
            union { uint4 v; unsigned short s[8]; } p;
            p.v = *(const uint4*)(mp + ((long long)g << 22) + idx);
#pragma unroll
            for (int j = 0; j < 8; ++j) o[j] += bf2f(p.s[j]) * linv;
        }
#pragma unroll
        for (int j = 0; j < 8; ++j) o[j] *= 0.0625f;
        if (isf) {
            float* dst = (float*)dout + 4194304 + idx;
            float4 a = {o[0], o[1], o[2], o[3]}, bq = {o[4], o[5], o[6], o[7]};
            *(float4*)dst = a;
            *(float4*)(dst + 4) = bq;
        } else {
            union { uint4 v; unsigned short s[8]; } pk;
#pragma unroll
            for (int j = 0; j < 8; ++j) pk.s[j] = f2bf(o[j]);
            *(uint4*)((unsigned short*)dout + 4194304 + idx) = pk.v;
        }
    }
}

// ---------------------------------------------------------------------------
// Fallback fused attention (non-DIRECT ws sizes), unchanged from R7.
// ---------------------------------------------------------------------------
template<bool DIRECT>
__global__ __launch_bounds__(256, DIRECT ? 4 : 2)
void k_attn(const unsigned short* __restrict__ qw,
        const unsigned short* __restrict__ kw, const unsigned short* __restrict__ vtw,
        unsigned short* __restrict__ ows, unsigned short* __restrict__ mpart,
        float* __restrict__ lsumg, int hpg)
{
    __shared__ unsigned short P[4][16][16][16];   // 32 KB, per-wave [kt][row][col16]
    __shared__ float red[4][16];
    float (*obuf)[16][65] = (float (*)[16][65])&P[0][0][0][0];   // alias, used late
    const int b = blockIdx.y, q0 = blockIdx.x * 16, g = blockIdx.z;
    const int tid = threadIdx.x, w = tid >> 6, lane = tid & 63, quad = lane >> 4, li = lane & 15;

    float mean_acc[DIRECT ? 1 : 64];
    if constexpr (!DIRECT) {
#pragma unroll
        for (int i = 0; i < 64; ++i) mean_acc[i] = 0.f;
    }

    for (int hh = 0; hh < hpg; ++hh) {
        const int h = g * hpg + hh;
        const unsigned short* qb = qw + ((long long)(b * 16 + h) * 1024 + q0 + li) * 64 + quad * 8;
        bf16x8 qf0 = *(const bf16x8*)qb;
        bf16x8 qf1 = *(const bf16x8*)(qb + 32);

        // ---- score pass: MFMA -> exp -> P(LDS) + row-sum ----
        float rsum[4] = {0.f, 0.f, 0.f, 0.f};
        const unsigned short* kbh = kw + (long long)(b * 16 + h) * 65536;
#pragma unroll
        for (int kt = 0; kt < 16; ++kt) {
            const unsigned short* kb = kbh + (w * 256 + kt * 16 + li) * 64 + quad * 8;
            bf16x8 kf0 = *(const bf16x8*)kb;
            bf16x8 kf1 = *(const bf16x8*)(kb + 32);
            f32x4 a = {0.f, 0.f, 0.f, 0.f};
            a = MFMA16(qf0, kf0, a);
            a = MFMA16(qf1, kf1, a);
#pragma unroll
            for (int r = 0; r < 4; ++r) {
                float p = __expf(a[r]);
                rsum[r] += p;
                P[w][kt][quad * 4 + r][li] = f2bf(p);
            }
        }
#pragma unroll
        for (int r = 0; r < 4; ++r) {
            float s = rsum[r];
#pragma unroll
            for (int d = 1; d < 16; d <<= 1) s += __shfl_xor(s, d, 64);
            rsum[r] = s;
        }
        if (li == 0) {
#pragma unroll
            for (int r = 0; r < 4; ++r) red[w][quad * 4 + r] = rsum[r];
        }
        // ---- PV on UNNORMALIZED P (own-wave LDS, pre-barrier) ----
        f32x4 oacc[4] = {{0,0,0,0},{0,0,0,0},{0,0,0,0},{0,0,0,0}};
        const unsigned short* vbh = vtw + (long long)(b * 16 + h) * 65536;
        unsigned short* mp = mpart + ((long long)h << 22);
        const long long rowoff2 = (long long)(b * 1024 + q0 + li) * 1024 + w * 256;
#pragma unroll
        for (int t = 0; t < 8; ++t) {
            union { bf16x8 v; uint4 u; } pa;
            pa.v = *(const bf16x8*)&P[w][2 * t + (quad >> 1)][li][(quad & 1) * 8];
            if constexpr (DIRECT)
                *(uint4*)(mp + rowoff2 + t * 32 + quad * 8) = pa.u;
            const int sv0 = w * 256 + t * 32;
#pragma unroll
            for (int nt = 0; nt < 4; ++nt) {
                const unsigned short* vb = vbh + (nt * 16 + li) * 1024 + sv0 + quad * 8;
                bf16x8 vf = *(const bf16x8*)vb;
                oacc[nt] = MFMA16(pa.v, vf, oacc[nt]);
            }
        }
        __syncthreads();                          // red ready AND all P reads done
        float linv[4];
#pragma unroll
        for (int r = 0; r < 4; ++r)
            linv[r] = 1.f / (red[0][quad * 4 + r] + red[1][quad * 4 + r] +
                             red[2][quad * 4 + r] + red[3][quad * 4 + r]);
        if constexpr (DIRECT) {
            if (tid < 16) {
                float s = red[0][tid] + red[1][tid] + red[2][tid] + red[3][tid];
                lsumg[((long long)h << 12) + b * 1024 + q0 + tid] = s;
            }
        } else {
            float lrow = 1.f / (red[0][li] + red[1][li] + red[2][li] + red[3][li]);
#pragma unroll
            for (int t = 0; t < 8; ++t) {
                union { bf16x8 v; unsigned short s[8]; } pa;
                pa.v = *(const bf16x8*)&P[w][2 * t + (quad >> 1)][li][(quad & 1) * 8];
#pragma unroll
                for (int j = 0; j < 8; ++j) mean_acc[t * 8 + j] += bf2f(pa.s[j]) * lrow;
            }
            __syncthreads();                      // all P reads done before obuf alias
        }
#pragma unroll
        for (int nt = 0; nt < 4; ++nt)
#pragma unroll
            for (int r = 0; r < 4; ++r)
                obuf[w][quad * 4 + r][nt * 16 + li] = oacc[nt][r] * linv[r];
        __syncthreads();
        {
            int row = tid >> 4, c4 = (tid & 15) * 4;
            union { uint2 v2; unsigned short s[4]; } pk;
#pragma unroll
            for (int j = 0; j < 4; ++j) {
                float s = obuf[0][row][c4 + j] + obuf[1][row][c4 + j] +
                          obuf[2][row][c4 + j] + obuf[3][row][c4 + j];
                pk.s[j] = f2bf(s);
            }
            *(uint2*)(ows + ((long long)(b * 1024) + q0 + row) * 1024 + h * 64 + c4) = pk.v2;
        }
        if (hh + 1 < hpg) __syncthreads();        // obuf reads done before next head
    }
    if constexpr (!DIRECT) {
        unsigned short* mp = mpart + ((long long)g << 22);
        long long rowoff2 = (long long)(b * 1024 + q0 + li) * 1024 + w * 256;
#pragma unroll
        for (int t = 0; t < 8; ++t) {
            union { uint4 v; unsigned short s[8]; } u;
#pragma unroll
            for (int j = 0; j < 8; ++j) u.s[j] = f2bf(mean_acc[t * 8 + j]);
            *(uint4*)(mp + rowoff2 + t * 32 + quad * 8) = u.v;
        }
    }
}

// ---------------------------------------------------------------------------
// Fallback combine (normalized partial planes, ng groups), unchanged.
// ---------------------------------------------------------------------------
__global__ __launch_bounds__(256) void k_mean_combine(const unsigned short* __restrict__ mp,
        void* __restrict__ dout, const int* __restrict__ flag, int ng)
{
    const int isf = *flag;
    long long idx = ((long long)blockIdx.x * 256 + threadIdx.x) * 8;
    float o[8] = {0, 0, 0, 0, 0, 0, 0, 0};
    for (int g = 0; g < ng; ++g) {
        union { uint4 v; unsigned short s[8]; } p;
        p.v = *(const uint4*)(mp + ((long long)g << 22) + idx);
#pragma unroll
        for (int j = 0; j < 8; ++j) o[j] += bf2f(p.s[j]);
    }
#pragma unroll
    for (int j = 0; j < 8; ++j) o[j] *= 0.0625f;
    if (isf) {
        float* dst = (float*)dout + 4194304 + idx;
        float4 a = {o[0], o[1], o[2], o[3]}, bq = {o[4], o[5], o[6], o[7]};
        *(float4*)dst = a;
        *(float4*)(dst + 4) = bq;
    } else {
        union { uint4 v; unsigned short s[8]; } pk;
#pragma unroll
        for (int j = 0; j < 8; ++j) pk.s[j] = f2bf(o[j]);
        *(uint4*)((unsigned short*)dout + 4194304 + idx) = pk.v;
    }
}

// ---------------------------------------------------------------------------
// Output projection: 128x128 tiles, grid (32, 8). (tier-2 / fallback path)
// ---------------------------------------------------------------------------
__global__ __launch_bounds__(256) void k_gemm_out(const unsigned short* __restrict__ aws,
        const unsigned short* __restrict__ w_outT, const unsigned short* __restrict__ b_out,
        void* __restrict__ dout, const int* __restrict__ flag)
{
    __shared__ unsigned short sm[17408];
    unsigned short (*lC)[136] = (unsigned short (*)[136])sm;
    const int gm0 = blockIdx.x * 128, gn0 = blockIdx.y * 128;
    const int isf = *flag;
    f32x4 acc[4][4];
#pragma unroll
    for (int i = 0; i < 4; ++i)
#pragma unroll
        for (int j = 0; j < 4; ++j) acc[i][j] = (f32x4){0.f, 0.f, 0.f, 0.f};
    gemm_core(aws + (long long)gm0 * 1024, 1024, w_outT + (long long)gn0 * 1024, 1024, 1024,
              sm, sm + 4096, acc);

    const int tid = threadIdx.x, w = tid >> 6, wr = w >> 1, wc = w & 1;
    const int lane = tid & 63, quad = lane >> 4, li = lane & 15;
#pragma unroll
    for (int at = 0; at < 4; ++at)
#pragma unroll
        for (int bt = 0; bt < 4; ++bt)
#pragma unroll
            for (int r = 0; r < 4; ++r) {
                int row = wr * 64 + at * 16 + quad * 4 + r;
                int col = wc * 64 + bt * 16 + li;
                lC[row][col] = f2bf(acc[at][bt][r] + bf2f(b_out[gn0 + col]));
            }
    __syncthreads();
    int mm = tid >> 1, ch = (tid & 1) * 64;
    if (isf) {
        float* dst = (float*)dout + (long long)(gm0 + mm) * 1024 + gn0 + ch;
#pragma unroll
        for (int j4 = 0; j4 < 16; ++j4) {
            float4 f;
            f.x = bf2f(lC[mm][ch + j4 * 4 + 0]);
            f.y = bf2f(lC[mm][ch + j4 * 4 + 1]);
            f.z = bf2f(lC[mm][ch + j4 * 4 + 2]);
            f.w = bf2f(lC[mm][ch + j4 * 4 + 3]);
            *(float4*)(dst + j4 * 4) = f;
        }
    } else {
        unsigned short* dst = (unsigned short*)dout + (long long)(gm0 + mm) * 1024 + gn0 + ch;
#pragma unroll
        for (int j = 0; j < 8; ++j)
            *(uint4*)(dst + j * 8) = *(const uint4*)&lC[mm][ch + j * 8];
    }
}

// ---------------------------------------------------------------------------
// ws layout (shorts): [flag 256][xb/ows 4.19M][b_in 3072][b_out 1024]
// [w_outT 1.05M][qws 4.19M][kws 4.19M][vtws 4.19M][w_inT 3.15M | mpart 16 x
// 4.19M (alias)]. mpart ends at byte 169,878,016 (proven DIRECT threshold).
// Tier-1 (ws_size >= 170,140,160): linv (256KB) AFTER mpart in ws -> fused
// epilogue. Tier-2: linv at start of d_out, separate launches (R8 path).
// Fallback: ng-group path. Preamble is ONE k_prep launch in all tiers.
// ---------------------------------------------------------------------------
extern "C" void kernel_launch(void* const* d_in, const int* in_sizes, int n_in,
                              void* d_out, int out_size, void* d_ws, size_t ws_size,
                              hipStream_t stream)
{
    int* flag = (int*)d_ws;
    unsigned short* xb     = (unsigned short*)d_ws + 256;      // 4,194,304
    unsigned short* b_inb  = xb + 4194304;                     // 3,072
    unsigned short* b_outb = b_inb + 3072;                     // 1,024
    unsigned short* w_outT = b_outb + 1024;                    // 1,048,576
    unsigned short* qws    = w_outT + 1048576;                 // 4,194,304
    unsigned short* kws    = qws + 4194304;                    // 4,194,304
    unsigned short* vtws   = kws + 4194304;                    // 4,194,304
    unsigned short* w_inT  = vtws + 4194304;                   // 3,145,728 (dead after qkv)
    unsigned short* mpart  = w_inT;                            // 16 x 4,194,304 (alias)
    unsigned short* ows    = xb;                               // reuse x staging (dead)
    float* lsumf           = (float*)d_out;                    // tier-2 linv scratch
    float* linv_ws         = (float*)(mpart + 67108864);       // tier-1 linv (after mpart)

    k_prep<<<3073, 256, 0, stream>>>(d_in[0], d_in[1], d_in[2], d_in[4], d_in[3],
                                     xb, w_inT, w_outT, flag);
    k_gemm_qkv<<<dim3(32, 24), 256, 0, stream>>>(xb, w_inT, b_inb, qws, kws, vtws);

    if (ws_size >= 170140160ull) {                             // tier-1: fused epilogue
        k_attn_d<<<dim3(8, 4, 16), 256, 0, stream>>>(qws, kws, vtws, ows, mpart, linv_ws);
        k_out_fused<<<2304, 256, 0, stream>>>(ows, w_outT, b_outb, mpart, linv_ws, d_out, flag);
    } else if (ws_size >= 169878016ull) {                      // tier-2: proven R8 path
        k_attn_d<<<dim3(8, 4, 16), 256, 0, stream>>>(qws, kws, vtws, ows, mpart, lsumf);
        k_mean_combine_linv<<<2048, 256, 0, stream>>>(mpart, lsumf, d_out, flag);
        k_gemm_out<<<dim3(32, 8), 256, 0, stream>>>(ows, w_outT, b_outb, d_out, flag);
    } else {
        int ng = (ws_size >= 102769152ull) ? 8 : 4;
        k_attn<false><<<dim3(64, 4, ng), 256, 0, stream>>>(qws, kws, vtws, ows, mpart, lsumf, 16 / ng);
        k_mean_combine<<<2048, 256, 0, stream>>>(mpart, d_out, flag, ng);
        k_gemm_out<<<dim3(32, 8), 256, 0, stream>>>(ows, w_outT, b_outb, d_out, flag);
    }
}